// Round 1
// baseline (614.441 us; speedup 1.0000x reference)
//
#include <hip/hip_runtime.h>
#include <math.h>

// ============================================================================
// BitNet transformer block, MI355X (gfx950).
// R0 theory: all bitlinears -> alpha * (Qact(x)_bf16 @ sign(w)_bf16^T), MFMA
// 16x16x32 bf16, 128x128 tiles, global_load_lds(16B) + XOR-swizzled LDS.
// Flash attention (causal), fused act_quant epilogues.
// ws layout (bytes, MB=2^20):    need ~121 MB total
//   0..32MB   sign weights (wq,wk,wv @0/2/4MB, wo @6MB, w1 @8, w2 @16, w3 @24)
//   32MB      alpha partials (7*256 f32) ; alphas (7 f32) at +16KB
//   33MB      x1 fp32 [4096,1024]
//   49MB      hq / h2q bf16 [4096,1024]
//   57MB      QKV fused bf16 [4096,3072]  (later aliased by y1/zq [4096,4096])
//   81MB      y (attn out, quantized) bf16 [4096,1024]
//   89MB      y2 bf16 [4096,4096]
// ============================================================================

typedef unsigned short u16;
typedef __attribute__((ext_vector_type(4))) float f32x4;
typedef __attribute__((ext_vector_type(4))) unsigned short u16x4;
typedef __attribute__((ext_vector_type(8))) unsigned short u16x8;
typedef __attribute__((ext_vector_type(8))) __bf16 bf16x8;

#define DEV static __device__ __forceinline__

DEV float bf2f(u16 u) { union { unsigned i; float f; } c; c.i = ((unsigned)u) << 16; return c.f; }
DEV u16 f2bf(float f) { __bf16 b = (__bf16)f; return __builtin_bit_cast(u16, b); }

DEV void gload16(const void* g, void* l) {
  // global -> LDS direct, 16B per lane. LDS dst must be wave-uniform base;
  // HW writes base + lane*16 (guide §5). Source is per-lane (pre-swizzled).
  __builtin_amdgcn_global_load_lds((__attribute__((address_space(1))) void*)g,
                                   (__attribute__((address_space(3))) void*)l,
                                   16, 0, 0);
}

// ---------------------------------------------------------------------------
// Weight prep: sign(w) -> bf16 {+1,-1,0}, block-partial sums of |w|.
// Deterministic two-stage reduction (no float atomics).
// ---------------------------------------------------------------------------
__global__ __launch_bounds__(256) void convert_sign(
    const float* __restrict__ w, u16* __restrict__ sgn,
    float* __restrict__ partial, int n4) {
  __shared__ float red[4];
  float s = 0.f;
  for (int i = blockIdx.x * 256 + threadIdx.x; i < n4; i += 256 * 256) {
    f32x4 v = ((const f32x4*)w)[i];
    u16x4 o;
#pragma unroll
    for (int j = 0; j < 4; ++j) {
      float f = v[j];
      o[j] = f > 0.f ? (u16)0x3F80 : (f < 0.f ? (u16)0xBF80 : (u16)0);
      s += fabsf(f);
    }
    ((u16x4*)sgn)[i] = o;
  }
#pragma unroll
  for (int off = 32; off >= 1; off >>= 1) s += __shfl_xor(s, off);
  if ((threadIdx.x & 63) == 0) red[threadIdx.x >> 6] = s;
  __syncthreads();
  if (threadIdx.x == 0) partial[blockIdx.x] = red[0] + red[1] + red[2] + red[3];
}

__global__ __launch_bounds__(256) void finalize_alpha(
    const float* __restrict__ partial, float* __restrict__ alphas) {
  __shared__ float red[4];
  int wi = blockIdx.x;  // 0..6
  float v = partial[wi * 256 + threadIdx.x];
#pragma unroll
  for (int off = 32; off >= 1; off >>= 1) v += __shfl_xor(v, off);
  if ((threadIdx.x & 63) == 0) red[threadIdx.x >> 6] = v;
  __syncthreads();
  if (threadIdx.x == 0)
    alphas[wi] = (red[0] + red[1] + red[2] + red[3]) *
                 (wi < 4 ? (1.f / 1048576.f) : (1.f / 4194304.f));
}

// ---------------------------------------------------------------------------
// RMSNorm + act_quant (group 64) fused. One block per row of 1024.
// ---------------------------------------------------------------------------
__global__ __launch_bounds__(256) void rmsnorm_quant(
    const float* __restrict__ x, const float* __restrict__ g, u16* __restrict__ out) {
  __shared__ float red[4];
  const int row = blockIdx.x, t = threadIdx.x;
  f32x4 v = ((const f32x4*)(x + (size_t)row * 1024))[t];
  float ss = v[0] * v[0] + v[1] * v[1] + v[2] * v[2] + v[3] * v[3];
#pragma unroll
  for (int off = 32; off >= 1; off >>= 1) ss += __shfl_xor(ss, off);
  if ((t & 63) == 0) red[t >> 6] = ss;
  __syncthreads();
  float tot = red[0] + red[1] + red[2] + red[3];
  float rinv = rsqrtf(tot * (1.f / 1024.f) + 1e-6f);
  f32x4 gg = ((const f32x4*)g)[t];
  float n[4];
#pragma unroll
  for (int j = 0; j < 4; ++j) n[j] = v[j] * rinv * gg[j];
  // group of 64 elems = 16 consecutive lanes (4 elems each)
  float gm = fmaxf(fmaxf(fabsf(n[0]), fabsf(n[1])), fmaxf(fabsf(n[2]), fabsf(n[3])));
#pragma unroll
  for (int off = 1; off <= 8; off <<= 1) gm = fmaxf(gm, __shfl_xor(gm, off));
  float s = fmaxf(gm, 1e-5f) / 127.0f;
  u16x4 o;
#pragma unroll
  for (int j = 0; j < 4; ++j) {
    float q = fminf(fmaxf(rintf(n[j] / s), -127.f), 127.f) * s;
    o[j] = f2bf(q);
  }
  ((u16x4*)out)[(size_t)row * 256 + t] = o;
}

// ---------------------------------------------------------------------------
// silu(y1)*y2 + act_quant (group 64). 1024 elems per block.
// ---------------------------------------------------------------------------
__global__ __launch_bounds__(256) void silu_mul_quant(
    const u16* __restrict__ y1, const u16* __restrict__ y2, u16* __restrict__ zq) {
  size_t base = (size_t)blockIdx.x * 1024 + threadIdx.x * 4;
  u16x4 a4 = *(const u16x4*)(y1 + base);
  u16x4 b4 = *(const u16x4*)(y2 + base);
  float z[4];
#pragma unroll
  for (int j = 0; j < 4; ++j) {
    float a = bf2f(a4[j]);
    z[j] = a / (1.f + __expf(-a)) * bf2f(b4[j]);
  }
  float gm = fmaxf(fmaxf(fabsf(z[0]), fabsf(z[1])), fmaxf(fabsf(z[2]), fabsf(z[3])));
#pragma unroll
  for (int off = 1; off <= 8; off <<= 1) gm = fmaxf(gm, __shfl_xor(gm, off));
  float s = fmaxf(gm, 1e-5f) / 127.0f;
  u16x4 o;
#pragma unroll
  for (int j = 0; j < 4; ++j) {
    float q = fminf(fmaxf(rintf(z[j] / s), -127.f), 127.f) * s;
    o[j] = f2bf(q);
  }
  *(u16x4*)(zq + base) = o;
}

// ---------------------------------------------------------------------------
// GEMM: C[M,N] = alpha[n-block] * (A[M,K] @ B[N,K]^T) (+ res), A,B bf16.
// 128x128 tile, BK=64, 4 waves (2x2 of 64x64), global_load_lds w=16,
// XOR-swizzle (chunk ^ (row&7)) applied on the GLOBAL source (rule #21),
// ds_read_b128 fragment loads with matching XOR on the read address.
// RES: fp32 out with residual; else bf16 out.
// ---------------------------------------------------------------------------
template <bool RES>
__global__ __launch_bounds__(256) void gemm_bt(
    const u16* __restrict__ A, const u16* __restrict__ B,
    const float* __restrict__ alpha, int ashift, const float* __restrict__ res,
    void* __restrict__ Cout, int M, int N, int K) {
  __shared__ u16 As[128 * 64];
  __shared__ u16 Bs[128 * 64];
  const int tid = threadIdx.x;
  const int l = tid & 63, w = tid >> 6;
  const int wm = w >> 1, wn = w & 1;
  const int lr = l & 15, lg = l >> 4;
  const int xorv = (l & 7) << 4;
  const int brow = blockIdx.y * 128;
  const int bcol = blockIdx.x * 128;
  const int src_chunk = (l & 7) ^ (l >> 3);  // slot^(row&7): inverse swizzle on source
  const int rl = w * 8 + (l >> 3);           // row (0..31) within a 32-row pass

  f32x4 acc[4][4];
#pragma unroll
  for (int i = 0; i < 4; ++i)
#pragma unroll
    for (int j = 0; j < 4; ++j) acc[i][j] = (f32x4){0.f, 0.f, 0.f, 0.f};

  const char* Ag = (const char*)A;
  const char* Bg = (const char*)B;
  const int nkt = K >> 6;
  for (int kt = 0; kt < nkt; ++kt) {
    __syncthreads();  // previous tile's reads complete
    const size_t kb = (size_t)kt * 128 + src_chunk * 16;  // byte offset along K
#pragma unroll
    for (int it = 0; it < 4; ++it)
      gload16(Ag + (size_t)(brow + it * 32 + rl) * (size_t)(K * 2) + kb,
              &As[(it * 32 + w * 8) * 64]);
#pragma unroll
    for (int it = 0; it < 4; ++it)
      gload16(Bg + (size_t)(bcol + it * 32 + rl) * (size_t)(K * 2) + kb,
              &Bs[(it * 32 + w * 8) * 64]);
    __syncthreads();  // compiler drains vmcnt(0) before barrier (guide §5)

    bf16x8 af[4][2], bfr[4][2];
#pragma unroll
    for (int mi = 0; mi < 4; ++mi)
#pragma unroll
      for (int ks = 0; ks < 2; ++ks) {
        int row = wm * 64 + mi * 16 + lr;  // row&7 == l&7
        af[mi][ks] = *(const bf16x8*)((const char*)As + row * 128 + ((ks * 64 + lg * 16) ^ xorv));
      }
#pragma unroll
    for (int ni = 0; ni < 4; ++ni)
#pragma unroll
      for (int ks = 0; ks < 2; ++ks) {
        int row = wn * 64 + ni * 16 + lr;
        bfr[ni][ks] = *(const bf16x8*)((const char*)Bs + row * 128 + ((ks * 64 + lg * 16) ^ xorv));
      }
#pragma unroll
    for (int ks = 0; ks < 2; ++ks)
#pragma unroll
      for (int mi = 0; mi < 4; ++mi)
#pragma unroll
        for (int ni = 0; ni < 4; ++ni)
          acc[mi][ni] = __builtin_amdgcn_mfma_f32_16x16x32_bf16(
              af[mi][ks], bfr[ni][ks], acc[mi][ni], 0, 0, 0);
  }

  const float scale = alpha[bcol >> ashift];  // per-1024-col alpha when fused QKV
#pragma unroll
  for (int mi = 0; mi < 4; ++mi)
#pragma unroll
    for (int ni = 0; ni < 4; ++ni)
#pragma unroll
      for (int r = 0; r < 4; ++r) {
        int row = brow + wm * 64 + mi * 16 + lg * 4 + r;  // C: row=(l>>4)*4+r
        int col = bcol + wn * 64 + ni * 16 + lr;          //    col=l&15
        float vv = acc[mi][ni][r] * scale;
        if (RES)
          ((float*)Cout)[(size_t)row * N + col] = res[(size_t)row * N + col] + vv;
        else
          ((u16*)Cout)[(size_t)row * N + col] = f2bf(vv);
      }
}

// ---------------------------------------------------------------------------
// Causal flash attention + fused act_quant epilogue.
// QKV fused layout [4096, 3072] bf16 (q|k|v per row). One block = (head, 64
// q-rows); 4 waves x 16 q-rows. K/V tiles 64x64 staged via global_load_lds
// (swizzled); scores via mfma(Q,K); P -> per-wave LDS (swizzled) -> A-frags;
// V frags via scalar ds_read_u16 (known ~4-way conflicts; R1 simplification).
// ---------------------------------------------------------------------------
__global__ __launch_bounds__(256) void attn_kernel(
    const u16* __restrict__ QKV, u16* __restrict__ Y) {
  __shared__ u16 Ks[64 * 64];
  __shared__ u16 Vs[64 * 64];
  __shared__ u16 Ps[4][16 * 64];

  const int tid = threadIdx.x;
  const int l = tid & 63, w = tid >> 6;
  const int lr = l & 15, lg = l >> 4;
  const int xorv = (l & 7) << 4;
  const int qt = gridDim.x - 1 - blockIdx.x;  // heavy blocks dispatched first
  const int h = blockIdx.y;
  const int src_chunk = (l & 7) ^ (l >> 3);
  const int rl = w * 8 + (l >> 3);
  const size_t RS = 3072;  // fused row stride (elems)

  // Q fragments in registers (row = l&15, k contiguous 8)
  const int qrow = qt * 64 + w * 16 + lr;
  bf16x8 qf[2];
#pragma unroll
  for (int ks = 0; ks < 2; ++ks)
    qf[ks] = __builtin_bit_cast(
        bf16x8, *(const u16x8*)(QKV + (size_t)qrow * RS + h * 64 + ks * 32 + lg * 8));

  f32x4 O[4];
#pragma unroll
  for (int ni = 0; ni < 4; ++ni) O[ni] = (f32x4){0.f, 0.f, 0.f, 0.f};
  float m[4] = {-3e38f, -3e38f, -3e38f, -3e38f};
  float lsum[4] = {0.f, 0.f, 0.f, 0.f};

  for (int kt = 0; kt <= qt; ++kt) {
    __syncthreads();
    {  // stage K,V 64x64 tiles (k at col 1024, v at col 2048 of fused buf)
      const size_t colb = (size_t)h * 128 + src_chunk * 16;
#pragma unroll
      for (int it = 0; it < 2; ++it) {
        size_t rowb = (size_t)(kt * 64 + it * 32 + rl) * (RS * 2);
        gload16((const char*)QKV + rowb + 2048 + colb, &Ks[(it * 32 + w * 8) * 64]);
        gload16((const char*)QKV + rowb + 4096 + colb, &Vs[(it * 32 + w * 8) * 64]);
      }
    }
    __syncthreads();

    // S = Q @ K^T
    f32x4 S[4];
#pragma unroll
    for (int ni = 0; ni < 4; ++ni) {
      S[ni] = (f32x4){0.f, 0.f, 0.f, 0.f};
#pragma unroll
      for (int ks = 0; ks < 2; ++ks) {
        bf16x8 kf = *(const bf16x8*)((const char*)Ks + (ni * 16 + lr) * 128 +
                                     ((ks * 64 + lg * 16) ^ xorv));
        S[ni] = __builtin_amdgcn_mfma_f32_16x16x32_bf16(qf[ks], kf, S[ni], 0, 0, 0);
      }
    }

    // scale + causal mask (diag tile only)
    const bool diag = (kt == qt);
    float sv[4][4];
#pragma unroll
    for (int ni = 0; ni < 4; ++ni)
#pragma unroll
      for (int r = 0; r < 4; ++r) {
        float s = S[ni][r] * 0.125f;
        if (diag && (ni * 16 + lr) > (w * 16 + lg * 4 + r)) s = -1e30f;
        sv[ni][r] = s;
      }

    // online softmax per row (row r lives on 16 lanes sharing lg)
    float p[4][4];
#pragma unroll
    for (int r = 0; r < 4; ++r) {
      float nm = fmaxf(fmaxf(sv[0][r], sv[1][r]), fmaxf(sv[2][r], sv[3][r]));
#pragma unroll
      for (int off = 1; off <= 8; off <<= 1) nm = fmaxf(nm, __shfl_xor(nm, off));
      float mn = fmaxf(m[r], nm);
      float fac = __expf(m[r] - mn);
      m[r] = mn;
      float rs = 0.f;
#pragma unroll
      for (int ni = 0; ni < 4; ++ni) {
        float pv = __expf(sv[ni][r] - mn);
        p[ni][r] = pv;
        rs += pv;
      }
#pragma unroll
      for (int off = 1; off <= 8; off <<= 1) rs += __shfl_xor(rs, off);
      lsum[r] = lsum[r] * fac + rs;
#pragma unroll
      for (int ni = 0; ni < 4; ++ni) O[ni][r] *= fac;
    }

    // P -> per-wave LDS (swizzled), then re-read as A-frags
#pragma unroll
    for (int ni = 0; ni < 4; ++ni)
#pragma unroll
      for (int r = 0; r < 4; ++r) {
        int prow = lg * 4 + r, pcol = ni * 16 + lr;
        *(u16*)((char*)&Ps[w][0] + prow * 128 + ((pcol * 2) ^ ((prow & 7) << 4))) =
            f2bf(p[ni][r]);
      }
    bf16x8 pa[2];
#pragma unroll
    for (int ks = 0; ks < 2; ++ks)
      pa[ks] = *(const bf16x8*)((const char*)&Ps[w][0] + lr * 128 +
                                ((ks * 64 + lg * 16) ^ xorv));

    // O += P @ V  (V frags: scalar gather from swizzled Vs)
#pragma unroll
    for (int ni = 0; ni < 4; ++ni) {
#pragma unroll
      for (int ks = 0; ks < 2; ++ks) {
        bf16x8 vf;
#pragma unroll
        for (int j = 0; j < 8; ++j) {
          int kk = ks * 32 + lg * 8 + j;
          int d = ni * 16 + lr;
          u16 u = *(const u16*)((const char*)Vs + kk * 128 + ((d * 2) ^ ((kk & 7) << 4)));
          vf[j] = __builtin_bit_cast(__bf16, u);
        }
        O[ni] = __builtin_amdgcn_mfma_f32_16x16x32_bf16(pa[ks], vf, O[ni], 0, 0, 0);
      }
    }
  }

  // epilogue: normalize + act_quant (group of 64 = this head's dims per row)
  float o[4][4];
#pragma unroll
  for (int ni = 0; ni < 4; ++ni)
#pragma unroll
    for (int r = 0; r < 4; ++r) o[ni][r] = O[ni][r] / lsum[r];
#pragma unroll
  for (int r = 0; r < 4; ++r) {
    float gm = fmaxf(fmaxf(fabsf(o[0][r]), fabsf(o[1][r])),
                     fmaxf(fabsf(o[2][r]), fabsf(o[3][r])));
#pragma unroll
    for (int off = 1; off <= 8; off <<= 1) gm = fmaxf(gm, __shfl_xor(gm, off));
    float s = fmaxf(gm, 1e-5f) / 127.0f;
#pragma unroll
    for (int ni = 0; ni < 4; ++ni)
      o[ni][r] = fminf(fmaxf(rintf(o[ni][r] / s), -127.f), 127.f) * s;
  }
#pragma unroll
  for (int ni = 0; ni < 4; ++ni)
#pragma unroll
    for (int r = 0; r < 4; ++r)
      Y[(size_t)(qt * 64 + w * 16 + lg * 4 + r) * 1024 + h * 64 + ni * 16 + lr] =
          f2bf(o[ni][r]);
}

// ---------------------------------------------------------------------------
extern "C" void kernel_launch(void* const* d_in, const int* in_sizes, int n_in,
                              void* d_out, int out_size, void* d_ws, size_t ws_size,
                              hipStream_t stream) {
  const float* x  = (const float*)d_in[0];
  const float* wq = (const float*)d_in[1];
  const float* wk = (const float*)d_in[2];
  const float* wv = (const float*)d_in[3];
  const float* wo = (const float*)d_in[4];
  const float* w1 = (const float*)d_in[5];
  const float* w2 = (const float*)d_in[6];
  const float* w3 = (const float*)d_in[7];
  const float* g1 = (const float*)d_in[8];
  const float* g2 = (const float*)d_in[9];

  char* ws = (char*)d_ws;
  const size_t MB = 1024 * 1024;
  u16* sWq = (u16*)(ws + 0 * MB);   // wq|wk|wv contiguous -> fused QKV GEMM
  u16* sWk = (u16*)(ws + 2 * MB);
  u16* sWv = (u16*)(ws + 4 * MB);
  u16* sWo = (u16*)(ws + 6 * MB);
  u16* sW1 = (u16*)(ws + 8 * MB);
  u16* sW2 = (u16*)(ws + 16 * MB);
  u16* sW3 = (u16*)(ws + 24 * MB);
  float* partial = (float*)(ws + 32 * MB);           // 7*256 floats
  float* alphas  = (float*)(ws + 32 * MB + 16384);   // 7 floats
  float* x1      = (float*)(ws + 33 * MB);           // fp32 [4096,1024]
  u16* hq        = (u16*)(ws + 49 * MB);             // bf16 [4096,1024]
  u16* qkv       = (u16*)(ws + 57 * MB);             // bf16 [4096,3072]
  u16* yb        = (u16*)(ws + 81 * MB);             // bf16 [4096,1024]
  u16* y1        = (u16*)(ws + 57 * MB);             // aliases qkv (dead by then)
  u16* y2        = (u16*)(ws + 89 * MB);             // bf16 [4096,4096]
  u16* zq        = y1;                               // in-place silu*mul quant

  // weight prep
  convert_sign<<<256, 256, 0, stream>>>(wq, sWq, partial + 0 * 256, 1048576 / 4);
  convert_sign<<<256, 256, 0, stream>>>(wk, sWk, partial + 1 * 256, 1048576 / 4);
  convert_sign<<<256, 256, 0, stream>>>(wv, sWv, partial + 2 * 256, 1048576 / 4);
  convert_sign<<<256, 256, 0, stream>>>(wo, sWo, partial + 3 * 256, 1048576 / 4);
  convert_sign<<<256, 256, 0, stream>>>(w1, sW1, partial + 4 * 256, 4194304 / 4);
  convert_sign<<<256, 256, 0, stream>>>(w2, sW2, partial + 5 * 256, 4194304 / 4);
  convert_sign<<<256, 256, 0, stream>>>(w3, sW3, partial + 6 * 256, 4194304 / 4);
  finalize_alpha<<<7, 256, 0, stream>>>(partial, alphas);

  // attention branch
  rmsnorm_quant<<<4096, 256, 0, stream>>>(x, g1, hq);
  gemm_bt<false><<<dim3(24, 32), 256, 0, stream>>>(hq, sWq, alphas, 10, nullptr,
                                                   qkv, 4096, 3072, 1024);
  attn_kernel<<<dim3(64, 16), 256, 0, stream>>>(qkv, yb);
  gemm_bt<true><<<dim3(8, 32), 256, 0, stream>>>(yb, sWo, alphas + 3, 31, x,
                                                 x1, 4096, 1024, 1024);
  // FFN branch
  rmsnorm_quant<<<4096, 256, 0, stream>>>(x1, g2, hq);
  gemm_bt<false><<<dim3(32, 32), 256, 0, stream>>>(hq, sW1, alphas + 4, 31, nullptr,
                                                   y1, 4096, 4096, 1024);
  gemm_bt<false><<<dim3(32, 32), 256, 0, stream>>>(hq, sW2, alphas + 5, 31, nullptr,
                                                   y2, 4096, 4096, 1024);
  silu_mul_quant<<<16384, 256, 0, stream>>>(y1, y2, zq);
  gemm_bt<true><<<dim3(8, 32), 256, 0, stream>>>(zq, sW3, alphas + 6, 31, x1,
                                                 (float*)d_out, 4096, 1024, 4096);
}

// Round 2
// 610.569 us; speedup vs baseline: 1.0063x; 1.0063x over previous
//
#include <hip/hip_runtime.h>
#include <math.h>

// ============================================================================
// BitNet transformer block, MI355X (gfx950).  Round 2.
// R1 -> R2: attention rebuilt: V pre-transposed to Vt[h][d][t] so PV B-frags
// are ds_read_b128 (was 64 scalar ds_read_u16/lane/iter, 4% MfmaUtil);
// 2 M-frags per wave (QBLK=128); w1|w2 fused into one N=8192 GEMM.
// ws layout (MB = 2^20), peak 121 MB:
//   0..32    sign weights (wq@0,wk@2,wv@4,wo@6, w1@8,w2@16 (contig), w3@24)
//   32..33   alpha partials (7*256 f32); alphas (7 f32) at +16KB
//   33..49   Vt bf16 [16][64][4096] (live transpose->attn), then x1 fp32
//   49..57   hq bf16 (live rmsnorm->gemm), then zq bf16 (silu->w3 gemm)
//   57..81   qkv bf16 [4096,3072] (live ->attn); then y1y2 [4096,8192] 57..121
//   81..89   yb bf16 (attn->wo gemm), then overlaid by y1y2
// ============================================================================

typedef unsigned short u16;
typedef __attribute__((ext_vector_type(4))) float f32x4;
typedef __attribute__((ext_vector_type(4))) unsigned short u16x4;
typedef __attribute__((ext_vector_type(8))) unsigned short u16x8;
typedef __attribute__((ext_vector_type(8))) __bf16 bf16x8;

#define DEV static __device__ __forceinline__

DEV float bf2f(u16 u) { union { unsigned i; float f; } c; c.i = ((unsigned)u) << 16; return c.f; }
DEV u16 f2bf(float f) { __bf16 b = (__bf16)f; return __builtin_bit_cast(u16, b); }

DEV void gload16(const void* g, void* l) {
  __builtin_amdgcn_global_load_lds((__attribute__((address_space(1))) void*)g,
                                   (__attribute__((address_space(3))) void*)l,
                                   16, 0, 0);
}

// ---------------------------------------------------------------------------
// Weight prep: sign(w) -> bf16 {+1,-1,0}, block-partial sums of |w|.
// ---------------------------------------------------------------------------
__global__ __launch_bounds__(256) void convert_sign(
    const float* __restrict__ w, u16* __restrict__ sgn,
    float* __restrict__ partial, int n4) {
  __shared__ float red[4];
  float s = 0.f;
  for (int i = blockIdx.x * 256 + threadIdx.x; i < n4; i += 256 * 256) {
    f32x4 v = ((const f32x4*)w)[i];
    u16x4 o;
#pragma unroll
    for (int j = 0; j < 4; ++j) {
      float f = v[j];
      o[j] = f > 0.f ? (u16)0x3F80 : (f < 0.f ? (u16)0xBF80 : (u16)0);
      s += fabsf(f);
    }
    ((u16x4*)sgn)[i] = o;
  }
#pragma unroll
  for (int off = 32; off >= 1; off >>= 1) s += __shfl_xor(s, off);
  if ((threadIdx.x & 63) == 0) red[threadIdx.x >> 6] = s;
  __syncthreads();
  if (threadIdx.x == 0) partial[blockIdx.x] = red[0] + red[1] + red[2] + red[3];
}

__global__ __launch_bounds__(256) void finalize_alpha(
    const float* __restrict__ partial, float* __restrict__ alphas) {
  __shared__ float red[4];
  int wi = blockIdx.x;  // 0..6
  float v = partial[wi * 256 + threadIdx.x];
#pragma unroll
  for (int off = 32; off >= 1; off >>= 1) v += __shfl_xor(v, off);
  if ((threadIdx.x & 63) == 0) red[threadIdx.x >> 6] = v;
  __syncthreads();
  if (threadIdx.x == 0)
    alphas[wi] = (red[0] + red[1] + red[2] + red[3]) *
                 (wi < 4 ? (1.f / 1048576.f) : (1.f / 4194304.f));
}

// ---------------------------------------------------------------------------
// RMSNorm + act_quant (group 64). One block per row of 1024.
// ---------------------------------------------------------------------------
__global__ __launch_bounds__(256) void rmsnorm_quant(
    const float* __restrict__ x, const float* __restrict__ g, u16* __restrict__ out) {
  __shared__ float red[4];
  const int row = blockIdx.x, t = threadIdx.x;
  f32x4 v = ((const f32x4*)(x + (size_t)row * 1024))[t];
  float ss = v[0] * v[0] + v[1] * v[1] + v[2] * v[2] + v[3] * v[3];
#pragma unroll
  for (int off = 32; off >= 1; off >>= 1) ss += __shfl_xor(ss, off);
  if ((t & 63) == 0) red[t >> 6] = ss;
  __syncthreads();
  float tot = red[0] + red[1] + red[2] + red[3];
  float rinv = rsqrtf(tot * (1.f / 1024.f) + 1e-6f);
  f32x4 gg = ((const f32x4*)g)[t];
  float n[4];
#pragma unroll
  for (int j = 0; j < 4; ++j) n[j] = v[j] * rinv * gg[j];
  float gm = fmaxf(fmaxf(fabsf(n[0]), fabsf(n[1])), fmaxf(fabsf(n[2]), fabsf(n[3])));
#pragma unroll
  for (int off = 1; off <= 8; off <<= 1) gm = fmaxf(gm, __shfl_xor(gm, off));
  float s = fmaxf(gm, 1e-5f) / 127.0f;
  u16x4 o;
#pragma unroll
  for (int j = 0; j < 4; ++j) {
    float q = fminf(fmaxf(rintf(n[j] / s), -127.f), 127.f) * s;
    o[j] = f2bf(q);
  }
  ((u16x4*)out)[(size_t)row * 256 + t] = o;
}

// ---------------------------------------------------------------------------
// silu(y1)*y2 + act_quant. y1y2 fused [4096, 8192]: y1 = cols 0..4095,
// y2 = cols 4096..8191. zq out [4096,4096].
// ---------------------------------------------------------------------------
__global__ __launch_bounds__(256) void silu_mul_quant(
    const u16* __restrict__ y1y2, u16* __restrict__ zq) {
  size_t idx = (size_t)blockIdx.x * 1024 + threadIdx.x * 4;  // 0..16M
  size_t row = idx >> 12, c = idx & 4095;
  u16x4 a4 = *(const u16x4*)(y1y2 + row * 8192 + c);
  u16x4 b4 = *(const u16x4*)(y1y2 + row * 8192 + 4096 + c);
  float z[4];
#pragma unroll
  for (int j = 0; j < 4; ++j) {
    float a = bf2f(a4[j]);
    z[j] = a / (1.f + __expf(-a)) * bf2f(b4[j]);
  }
  float gm = fmaxf(fmaxf(fabsf(z[0]), fabsf(z[1])), fmaxf(fabsf(z[2]), fabsf(z[3])));
#pragma unroll
  for (int off = 1; off <= 8; off <<= 1) gm = fmaxf(gm, __shfl_xor(gm, off));
  float s = fmaxf(gm, 1e-5f) / 127.0f;
  u16x4 o;
#pragma unroll
  for (int j = 0; j < 4; ++j) {
    float q = fminf(fmaxf(rintf(z[j] / s), -127.f), 127.f) * s;
    o[j] = f2bf(q);
  }
  *(u16x4*)(zq + idx) = o;
}

// ---------------------------------------------------------------------------
// V transpose: qkv[:,2048+h*64 .. +63] -> Vt[h][d][t]  ([16][64][4096] bf16).
// LDS-tiled 64x64, coalesced global read/write.
// ---------------------------------------------------------------------------
__global__ __launch_bounds__(256) void transpose_v(
    const u16* __restrict__ qkv, u16* __restrict__ Vt) {
  __shared__ u16 T[64][65];
  const int tt = blockIdx.x, h = blockIdx.y, tid = threadIdx.x;
#pragma unroll
  for (int i = 0; i < 2; ++i) {
    int idx = i * 2048 + tid * 8;
    int trow = idx >> 6, dcol = idx & 63;
    u16x8 v = *(const u16x8*)(qkv + (size_t)(tt * 64 + trow) * 3072 + 2048 + h * 64 + dcol);
#pragma unroll
    for (int j = 0; j < 8; ++j) T[dcol + j][trow] = v[j];
  }
  __syncthreads();
#pragma unroll
  for (int i = 0; i < 2; ++i) {
    int idx = i * 2048 + tid * 8;
    int drow = idx >> 6, tcol = idx & 63;
    u16x8 v;
#pragma unroll
    for (int j = 0; j < 8; ++j) v[j] = T[drow][tcol + j];
    *(u16x8*)(Vt + ((size_t)h * 64 + drow) * 4096 + tt * 64 + tcol) = v;
  }
}

// ---------------------------------------------------------------------------
// GEMM: C[M,N] = alpha[bcol>>ashift] * (A[M,K] @ B[N,K]^T) (+res).
// 128x128 tile, BK=64, 4 waves (2x2), global_load_lds w=16, XOR swizzle.
// ---------------------------------------------------------------------------
template <bool RES>
__global__ __launch_bounds__(256) void gemm_bt(
    const u16* __restrict__ A, const u16* __restrict__ B,
    const float* __restrict__ alpha, int ashift, const float* __restrict__ res,
    void* __restrict__ Cout, int M, int N, int K) {
  __shared__ u16 As[128 * 64];
  __shared__ u16 Bs[128 * 64];
  const int tid = threadIdx.x;
  const int l = tid & 63, w = tid >> 6;
  const int wm = w >> 1, wn = w & 1;
  const int lr = l & 15, lg = l >> 4;
  const int xorv = (l & 7) << 4;
  const int brow = blockIdx.y * 128;
  const int bcol = blockIdx.x * 128;
  const int src_chunk = (l & 7) ^ (l >> 3);
  const int rl = w * 8 + (l >> 3);

  f32x4 acc[4][4];
#pragma unroll
  for (int i = 0; i < 4; ++i)
#pragma unroll
    for (int j = 0; j < 4; ++j) acc[i][j] = (f32x4){0.f, 0.f, 0.f, 0.f};

  const char* Ag = (const char*)A;
  const char* Bg = (const char*)B;
  const int nkt = K >> 6;
  for (int kt = 0; kt < nkt; ++kt) {
    __syncthreads();
    const size_t kb = (size_t)kt * 128 + src_chunk * 16;
#pragma unroll
    for (int it = 0; it < 4; ++it)
      gload16(Ag + (size_t)(brow + it * 32 + rl) * (size_t)(K * 2) + kb,
              &As[(it * 32 + w * 8) * 64]);
#pragma unroll
    for (int it = 0; it < 4; ++it)
      gload16(Bg + (size_t)(bcol + it * 32 + rl) * (size_t)(K * 2) + kb,
              &Bs[(it * 32 + w * 8) * 64]);
    __syncthreads();

    bf16x8 af[4][2], bfr[4][2];
#pragma unroll
    for (int mi = 0; mi < 4; ++mi)
#pragma unroll
      for (int ks = 0; ks < 2; ++ks) {
        int row = wm * 64 + mi * 16 + lr;
        af[mi][ks] = *(const bf16x8*)((const char*)As + row * 128 + ((ks * 64 + lg * 16) ^ xorv));
      }
#pragma unroll
    for (int ni = 0; ni < 4; ++ni)
#pragma unroll
      for (int ks = 0; ks < 2; ++ks) {
        int row = wn * 64 + ni * 16 + lr;
        bfr[ni][ks] = *(const bf16x8*)((const char*)Bs + row * 128 + ((ks * 64 + lg * 16) ^ xorv));
      }
#pragma unroll
    for (int ks = 0; ks < 2; ++ks)
#pragma unroll
      for (int mi = 0; mi < 4; ++mi)
#pragma unroll
        for (int ni = 0; ni < 4; ++ni)
          acc[mi][ni] = __builtin_amdgcn_mfma_f32_16x16x32_bf16(
              af[mi][ks], bfr[ni][ks], acc[mi][ni], 0, 0, 0);
  }

  const float scale = alpha[bcol >> ashift];
#pragma unroll
  for (int mi = 0; mi < 4; ++mi)
#pragma unroll
    for (int ni = 0; ni < 4; ++ni)
#pragma unroll
      for (int r = 0; r < 4; ++r) {
        int row = brow + wm * 64 + mi * 16 + lg * 4 + r;
        int col = bcol + wn * 64 + ni * 16 + lr;
        float vv = acc[mi][ni][r] * scale;
        if (RES)
          ((float*)Cout)[(size_t)row * N + col] = res[(size_t)row * N + col] + vv;
        else
          ((u16*)Cout)[(size_t)row * N + col] = f2bf(vv);
      }
}

// ---------------------------------------------------------------------------
// Causal flash attention + act_quant epilogue.
// QBLK=128 (4 waves x 32 q-rows, 2 M-frags/wave), KVBLK=64.
// K tiles from fused qkv; V tiles from pre-transposed Vt (row = head dim d,
// contiguous along t) -> both operand reads are swizzled ds_read_b128.
// ---------------------------------------------------------------------------
__global__ __launch_bounds__(256) void attn_kernel(
    const u16* __restrict__ QKV, const u16* __restrict__ Vt, u16* __restrict__ Y) {
  __shared__ u16 Ks[64 * 64];   // [k-token 64][d 64] swizzled
  __shared__ u16 Vs[64 * 64];   // [d 64][k-token 64] swizzled
  __shared__ u16 Ps[4][32 * 64];

  const int tid = threadIdx.x;
  const int l = tid & 63, w = tid >> 6;
  const int lr = l & 15, lg = l >> 4;
  const int xorv = (l & 7) << 4;
  const int qt = gridDim.x - 1 - blockIdx.x;  // heavy blocks first
  const int h = blockIdx.y;
  const int src_chunk = (l & 7) ^ (l >> 3);
  const int rl = w * 8 + (l >> 3);

  // Q fragments: rows qt*128 + w*32 + mi*16 + lr, cols h*64 + ks*32 + lg*8
  const int qrow0 = qt * 128 + w * 32;
  bf16x8 qf[2][2];
#pragma unroll
  for (int mi = 0; mi < 2; ++mi)
#pragma unroll
    for (int ks = 0; ks < 2; ++ks)
      qf[mi][ks] = __builtin_bit_cast(
          bf16x8,
          *(const u16x8*)(QKV + (size_t)(qrow0 + mi * 16 + lr) * 3072 + h * 64 + ks * 32 + lg * 8));

  f32x4 O[2][4];
#pragma unroll
  for (int mi = 0; mi < 2; ++mi)
#pragma unroll
    for (int ni = 0; ni < 4; ++ni) O[mi][ni] = (f32x4){0.f, 0.f, 0.f, 0.f};
  float m[2][4], lsum[2][4];
#pragma unroll
  for (int mi = 0; mi < 2; ++mi)
#pragma unroll
    for (int r = 0; r < 4; ++r) { m[mi][r] = -3e38f; lsum[mi][r] = 0.f; }

  const int nkt = 2 * qt + 2;
  for (int kt = 0; kt < nkt; ++kt) {
    __syncthreads();
    {  // stage K [64 tok x 64 d] and Vt [64 d x 64 tok], both swizzled via src
#pragma unroll
      for (int it = 0; it < 2; ++it) {
        int krow = kt * 64 + it * 32 + rl;  // token index
        gload16((const char*)QKV + ((size_t)krow * 3072 + 1024 + h * 64) * 2 + src_chunk * 16,
                &Ks[(it * 32 + w * 8) * 64]);
        int drow = it * 32 + rl;  // head-dim index
        gload16((const char*)Vt + (((size_t)h * 64 + drow) * 4096 + kt * 64) * 2 + src_chunk * 16,
                &Vs[(it * 32 + w * 8) * 64]);
      }
    }
    __syncthreads();

    // S[mi][ni] = Q @ K^T
    f32x4 S[2][4];
#pragma unroll
    for (int ni = 0; ni < 4; ++ni) {
      bf16x8 kf[2];
#pragma unroll
      for (int ks = 0; ks < 2; ++ks)
        kf[ks] = *(const bf16x8*)((const char*)Ks + (ni * 16 + lr) * 128 +
                                  ((ks * 64 + lg * 16) ^ xorv));
#pragma unroll
      for (int mi = 0; mi < 2; ++mi) {
        S[mi][ni] = (f32x4){0.f, 0.f, 0.f, 0.f};
#pragma unroll
        for (int ks = 0; ks < 2; ++ks)
          S[mi][ni] = __builtin_amdgcn_mfma_f32_16x16x32_bf16(qf[mi][ks], kf[ks], S[mi][ni], 0, 0, 0);
      }
    }

    // scale + causal mask (only the last two k-tiles touch the diagonal)
    const bool diag = (kt >= 2 * qt);
#pragma unroll
    for (int mi = 0; mi < 2; ++mi)
#pragma unroll
      for (int ni = 0; ni < 4; ++ni)
#pragma unroll
        for (int r = 0; r < 4; ++r) {
          float s = S[mi][ni][r] * 0.125f;
          if (diag && (kt * 64 + ni * 16 + lr) > (qrow0 + mi * 16 + lg * 4 + r)) s = -1e30f;
          S[mi][ni][r] = s;
        }

    // online softmax per (mi, r); row lives on the 16 lanes sharing lg
#pragma unroll
    for (int mi = 0; mi < 2; ++mi)
#pragma unroll
      for (int r = 0; r < 4; ++r) {
        float nm = fmaxf(fmaxf(S[mi][0][r], S[mi][1][r]), fmaxf(S[mi][2][r], S[mi][3][r]));
#pragma unroll
        for (int off = 1; off <= 8; off <<= 1) nm = fmaxf(nm, __shfl_xor(nm, off));
        float mn = fmaxf(m[mi][r], nm);
        float fac = __expf(m[mi][r] - mn);
        m[mi][r] = mn;
        float rs = 0.f;
#pragma unroll
        for (int ni = 0; ni < 4; ++ni) {
          float pv = __expf(S[mi][ni][r] - mn);
          S[mi][ni][r] = pv;  // S now holds P
          rs += pv;
        }
#pragma unroll
        for (int off = 1; off <= 8; off <<= 1) rs += __shfl_xor(rs, off);
        lsum[mi][r] = lsum[mi][r] * fac + rs;
#pragma unroll
        for (int ni = 0; ni < 4; ++ni) O[mi][ni][r] *= fac;
      }

    // P -> per-wave LDS (swizzled) -> A-frags
#pragma unroll
    for (int mi = 0; mi < 2; ++mi)
#pragma unroll
      for (int ni = 0; ni < 4; ++ni)
#pragma unroll
        for (int r = 0; r < 4; ++r) {
          int prow = mi * 16 + lg * 4 + r, pcol = ni * 16 + lr;
          *(u16*)((char*)&Ps[w][0] + prow * 128 + ((pcol * 2) ^ ((prow & 7) << 4))) =
              f2bf(S[mi][ni][r]);
        }
    bf16x8 pa[2][2];
#pragma unroll
    for (int mi = 0; mi < 2; ++mi)
#pragma unroll
      for (int ks = 0; ks < 2; ++ks)
        pa[mi][ks] = *(const bf16x8*)((const char*)&Ps[w][0] + (mi * 16 + lr) * 128 +
                                      ((ks * 64 + lg * 16) ^ xorv));

    // O += P @ V : B-frag lane l = Vt_tile[d = ni*16+lr][k = ks*32+lg*8+j]
#pragma unroll
    for (int ni = 0; ni < 4; ++ni) {
      bf16x8 vf[2];
#pragma unroll
      for (int ks = 0; ks < 2; ++ks)
        vf[ks] = *(const bf16x8*)((const char*)Vs + (ni * 16 + lr) * 128 +
                                  ((ks * 64 + lg * 16) ^ xorv));
#pragma unroll
      for (int mi = 0; mi < 2; ++mi)
#pragma unroll
        for (int ks = 0; ks < 2; ++ks)
          O[mi][ni] = __builtin_amdgcn_mfma_f32_16x16x32_bf16(pa[mi][ks], vf[ks], O[mi][ni], 0, 0, 0);
    }
  }

  // epilogue: normalize + act_quant (group of 64 = this head's dims)
#pragma unroll
  for (int mi = 0; mi < 2; ++mi) {
    float o[4][4];
#pragma unroll
    for (int ni = 0; ni < 4; ++ni)
#pragma unroll
      for (int r = 0; r < 4; ++r) o[ni][r] = O[mi][ni][r] / lsum[mi][r];
#pragma unroll
    for (int r = 0; r < 4; ++r) {
      float gm = fmaxf(fmaxf(fabsf(o[0][r]), fabsf(o[1][r])),
                       fmaxf(fabsf(o[2][r]), fabsf(o[3][r])));
#pragma unroll
      for (int off = 1; off <= 8; off <<= 1) gm = fmaxf(gm, __shfl_xor(gm, off));
      float s = fmaxf(gm, 1e-5f) / 127.0f;
#pragma unroll
      for (int ni = 0; ni < 4; ++ni)
        o[ni][r] = fminf(fmaxf(rintf(o[ni][r] / s), -127.f), 127.f) * s;
    }
#pragma unroll
    for (int ni = 0; ni < 4; ++ni)
#pragma unroll
      for (int r = 0; r < 4; ++r)
        Y[(size_t)(qrow0 + mi * 16 + lg * 4 + r) * 1024 + h * 64 + ni * 16 + lr] =
            f2bf(o[ni][r]);
  }
}

// ---------------------------------------------------------------------------
extern "C" void kernel_launch(void* const* d_in, const int* in_sizes, int n_in,
                              void* d_out, int out_size, void* d_ws, size_t ws_size,
                              hipStream_t stream) {
  const float* x  = (const float*)d_in[0];
  const float* wq = (const float*)d_in[1];
  const float* wk = (const float*)d_in[2];
  const float* wv = (const float*)d_in[3];
  const float* wo = (const float*)d_in[4];
  const float* w1 = (const float*)d_in[5];
  const float* w2 = (const float*)d_in[6];
  const float* w3 = (const float*)d_in[7];
  const float* g1 = (const float*)d_in[8];
  const float* g2 = (const float*)d_in[9];

  char* ws = (char*)d_ws;
  const size_t MB = 1024 * 1024;
  u16* sWq   = (u16*)(ws + 0 * MB);
  u16* sWk   = (u16*)(ws + 2 * MB);
  u16* sWv   = (u16*)(ws + 4 * MB);
  u16* sWo   = (u16*)(ws + 6 * MB);
  u16* sW1   = (u16*)(ws + 8 * MB);    // w1|w2 contiguous -> fused [8192,1024]
  u16* sW2   = (u16*)(ws + 16 * MB);
  u16* sW3   = (u16*)(ws + 24 * MB);
  float* partial = (float*)(ws + 32 * MB);
  float* alphas  = (float*)(ws + 32 * MB + 16384);
  u16* Vt    = (u16*)(ws + 33 * MB);   // [16][64][4096], dead before x1 written
  float* x1  = (float*)(ws + 33 * MB); // fp32 [4096,1024] (after attn)
  u16* hq    = (u16*)(ws + 49 * MB);   // bf16 [4096,1024]
  u16* zq    = (u16*)(ws + 49 * MB);   // reuses hq slot (hq dead by silu)
  u16* qkv   = (u16*)(ws + 57 * MB);   // bf16 [4096,3072]
  u16* yb    = (u16*)(ws + 81 * MB);   // bf16 [4096,1024]
  u16* y1y2  = (u16*)(ws + 57 * MB);   // bf16 [4096,8192] (qkv,yb dead)

  // weight prep
  convert_sign<<<256, 256, 0, stream>>>(wq, sWq, partial + 0 * 256, 1048576 / 4);
  convert_sign<<<256, 256, 0, stream>>>(wk, sWk, partial + 1 * 256, 1048576 / 4);
  convert_sign<<<256, 256, 0, stream>>>(wv, sWv, partial + 2 * 256, 1048576 / 4);
  convert_sign<<<256, 256, 0, stream>>>(wo, sWo, partial + 3 * 256, 1048576 / 4);
  convert_sign<<<256, 256, 0, stream>>>(w1, sW1, partial + 4 * 256, 4194304 / 4);
  convert_sign<<<256, 256, 0, stream>>>(w2, sW2, partial + 5 * 256, 4194304 / 4);
  convert_sign<<<256, 256, 0, stream>>>(w3, sW3, partial + 6 * 256, 4194304 / 4);
  finalize_alpha<<<7, 256, 0, stream>>>(partial, alphas);

  // attention branch
  rmsnorm_quant<<<4096, 256, 0, stream>>>(x, g1, hq);
  gemm_bt<false><<<dim3(24, 32), 256, 0, stream>>>(hq, sWq, alphas, 10, nullptr,
                                                   qkv, 4096, 3072, 1024);
  transpose_v<<<dim3(64, 16), 256, 0, stream>>>(qkv, Vt);
  attn_kernel<<<dim3(32, 16), 256, 0, stream>>>(qkv, Vt, yb);
  gemm_bt<true><<<dim3(8, 32), 256, 0, stream>>>(yb, sWo, alphas + 3, 31, x,
                                                 x1, 4096, 1024, 1024);
  // FFN branch
  rmsnorm_quant<<<4096, 256, 0, stream>>>(x1, g2, hq);
  gemm_bt<false><<<dim3(64, 32), 256, 0, stream>>>(hq, sW1, alphas + 4, 12, nullptr,
                                                   y1y2, 4096, 8192, 1024);
  silu_mul_quant<<<16384, 256, 0, stream>>>(y1y2, zq);
  gemm_bt<true><<<dim3(8, 32), 256, 0, stream>>>(zq, sW3, alphas + 6, 31, x1,
                                                 (float*)d_out, 4096, 1024, 4096);
}

// Round 3
// 479.469 us; speedup vs baseline: 1.2815x; 1.2734x over previous
//
#include <hip/hip_runtime.h>
#include <math.h>

// ============================================================================
// BitNet transformer block, MI355X (gfx950).  Round 3.
// R2 -> R3: attention makespan fix:
//  (a) complementary q-tile pairing (block does qt=p and qt=31-p): every
//      block does exactly 68 k-iterations (was: worst CU 128, avg 33).
//  (b) double-buffered K/V LDS with raw s_barrier + counted vmcnt(4)
//      (prefetch next tile during compute; no vmcnt(0) drain in loop).
// ws layout (MB = 2^20), peak 121 MB:
//   0..32    sign weights (wq@0,wk@2,wv@4,wo@6, w1@8,w2@16 (contig), w3@24)
//   32..33   alpha partials (7*256 f32); alphas (7 f32) at +16KB
//   33..49   Vt bf16 [16][64][4096] (live transpose->attn), then x1 fp32
//   49..57   hq bf16 (live rmsnorm->gemm), then zq bf16 (silu->w3 gemm)
//   57..81   qkv bf16 [4096,3072] (live ->attn); then y1y2 [4096,8192] 57..121
//   81..89   yb bf16 (attn->wo gemm), then overlaid by y1y2
// ============================================================================

typedef unsigned short u16;
typedef __attribute__((ext_vector_type(4))) float f32x4;
typedef __attribute__((ext_vector_type(4))) unsigned short u16x4;
typedef __attribute__((ext_vector_type(8))) unsigned short u16x8;
typedef __attribute__((ext_vector_type(8))) __bf16 bf16x8;

#define DEV static __device__ __forceinline__

DEV float bf2f(u16 u) { union { unsigned i; float f; } c; c.i = ((unsigned)u) << 16; return c.f; }
DEV u16 f2bf(float f) { __bf16 b = (__bf16)f; return __builtin_bit_cast(u16, b); }

DEV void gload16(const void* g, void* l) {
  __builtin_amdgcn_global_load_lds((__attribute__((address_space(1))) void*)g,
                                   (__attribute__((address_space(3))) void*)l,
                                   16, 0, 0);
}

// ---------------------------------------------------------------------------
// Weight prep: sign(w) -> bf16 {+1,-1,0}, block-partial sums of |w|.
// ---------------------------------------------------------------------------
__global__ __launch_bounds__(256) void convert_sign(
    const float* __restrict__ w, u16* __restrict__ sgn,
    float* __restrict__ partial, int n4) {
  __shared__ float red[4];
  float s = 0.f;
  for (int i = blockIdx.x * 256 + threadIdx.x; i < n4; i += 256 * 256) {
    f32x4 v = ((const f32x4*)w)[i];
    u16x4 o;
#pragma unroll
    for (int j = 0; j < 4; ++j) {
      float f = v[j];
      o[j] = f > 0.f ? (u16)0x3F80 : (f < 0.f ? (u16)0xBF80 : (u16)0);
      s += fabsf(f);
    }
    ((u16x4*)sgn)[i] = o;
  }
#pragma unroll
  for (int off = 32; off >= 1; off >>= 1) s += __shfl_xor(s, off);
  if ((threadIdx.x & 63) == 0) red[threadIdx.x >> 6] = s;
  __syncthreads();
  if (threadIdx.x == 0) partial[blockIdx.x] = red[0] + red[1] + red[2] + red[3];
}

__global__ __launch_bounds__(256) void finalize_alpha(
    const float* __restrict__ partial, float* __restrict__ alphas) {
  __shared__ float red[4];
  int wi = blockIdx.x;  // 0..6
  float v = partial[wi * 256 + threadIdx.x];
#pragma unroll
  for (int off = 32; off >= 1; off >>= 1) v += __shfl_xor(v, off);
  if ((threadIdx.x & 63) == 0) red[threadIdx.x >> 6] = v;
  __syncthreads();
  if (threadIdx.x == 0)
    alphas[wi] = (red[0] + red[1] + red[2] + red[3]) *
                 (wi < 4 ? (1.f / 1048576.f) : (1.f / 4194304.f));
}

// ---------------------------------------------------------------------------
// RMSNorm + act_quant (group 64). One block per row of 1024.
// ---------------------------------------------------------------------------
__global__ __launch_bounds__(256) void rmsnorm_quant(
    const float* __restrict__ x, const float* __restrict__ g, u16* __restrict__ out) {
  __shared__ float red[4];
  const int row = blockIdx.x, t = threadIdx.x;
  f32x4 v = ((const f32x4*)(x + (size_t)row * 1024))[t];
  float ss = v[0] * v[0] + v[1] * v[1] + v[2] * v[2] + v[3] * v[3];
#pragma unroll
  for (int off = 32; off >= 1; off >>= 1) ss += __shfl_xor(ss, off);
  if ((t & 63) == 0) red[t >> 6] = ss;
  __syncthreads();
  float tot = red[0] + red[1] + red[2] + red[3];
  float rinv = rsqrtf(tot * (1.f / 1024.f) + 1e-6f);
  f32x4 gg = ((const f32x4*)g)[t];
  float n[4];
#pragma unroll
  for (int j = 0; j < 4; ++j) n[j] = v[j] * rinv * gg[j];
  float gm = fmaxf(fmaxf(fabsf(n[0]), fabsf(n[1])), fmaxf(fabsf(n[2]), fabsf(n[3])));
#pragma unroll
  for (int off = 1; off <= 8; off <<= 1) gm = fmaxf(gm, __shfl_xor(gm, off));
  float s = fmaxf(gm, 1e-5f) / 127.0f;
  u16x4 o;
#pragma unroll
  for (int j = 0; j < 4; ++j) {
    float q = fminf(fmaxf(rintf(n[j] / s), -127.f), 127.f) * s;
    o[j] = f2bf(q);
  }
  ((u16x4*)out)[(size_t)row * 256 + t] = o;
}

// ---------------------------------------------------------------------------
// silu(y1)*y2 + act_quant. y1y2 fused [4096, 8192].
// ---------------------------------------------------------------------------
__global__ __launch_bounds__(256) void silu_mul_quant(
    const u16* __restrict__ y1y2, u16* __restrict__ zq) {
  size_t idx = (size_t)blockIdx.x * 1024 + threadIdx.x * 4;  // 0..16M
  size_t row = idx >> 12, c = idx & 4095;
  u16x4 a4 = *(const u16x4*)(y1y2 + row * 8192 + c);
  u16x4 b4 = *(const u16x4*)(y1y2 + row * 8192 + 4096 + c);
  float z[4];
#pragma unroll
  for (int j = 0; j < 4; ++j) {
    float a = bf2f(a4[j]);
    z[j] = a / (1.f + __expf(-a)) * bf2f(b4[j]);
  }
  float gm = fmaxf(fmaxf(fabsf(z[0]), fabsf(z[1])), fmaxf(fabsf(z[2]), fabsf(z[3])));
#pragma unroll
  for (int off = 1; off <= 8; off <<= 1) gm = fmaxf(gm, __shfl_xor(gm, off));
  float s = fmaxf(gm, 1e-5f) / 127.0f;
  u16x4 o;
#pragma unroll
  for (int j = 0; j < 4; ++j) {
    float q = fminf(fmaxf(rintf(z[j] / s), -127.f), 127.f) * s;
    o[j] = f2bf(q);
  }
  *(u16x4*)(zq + idx) = o;
}

// ---------------------------------------------------------------------------
// V transpose: qkv[:,2048+h*64 .. +63] -> Vt[h][d][t]  ([16][64][4096] bf16).
// ---------------------------------------------------------------------------
__global__ __launch_bounds__(256) void transpose_v(
    const u16* __restrict__ qkv, u16* __restrict__ Vt) {
  __shared__ u16 T[64][65];
  const int tt = blockIdx.x, h = blockIdx.y, tid = threadIdx.x;
#pragma unroll
  for (int i = 0; i < 2; ++i) {
    int idx = i * 2048 + tid * 8;
    int trow = idx >> 6, dcol = idx & 63;
    u16x8 v = *(const u16x8*)(qkv + (size_t)(tt * 64 + trow) * 3072 + 2048 + h * 64 + dcol);
#pragma unroll
    for (int j = 0; j < 8; ++j) T[dcol + j][trow] = v[j];
  }
  __syncthreads();
#pragma unroll
  for (int i = 0; i < 2; ++i) {
    int idx = i * 2048 + tid * 8;
    int drow = idx >> 6, tcol = idx & 63;
    u16x8 v;
#pragma unroll
    for (int j = 0; j < 8; ++j) v[j] = T[drow][tcol + j];
    *(u16x8*)(Vt + ((size_t)h * 64 + drow) * 4096 + tt * 64 + tcol) = v;
  }
}

// ---------------------------------------------------------------------------
// GEMM: C[M,N] = alpha[bcol>>ashift] * (A[M,K] @ B[N,K]^T) (+res).
// 128x128 tile, BK=64, 4 waves (2x2), global_load_lds w=16, XOR swizzle.
// ---------------------------------------------------------------------------
template <bool RES>
__global__ __launch_bounds__(256) void gemm_bt(
    const u16* __restrict__ A, const u16* __restrict__ B,
    const float* __restrict__ alpha, int ashift, const float* __restrict__ res,
    void* __restrict__ Cout, int M, int N, int K) {
  __shared__ u16 As[128 * 64];
  __shared__ u16 Bs[128 * 64];
  const int tid = threadIdx.x;
  const int l = tid & 63, w = tid >> 6;
  const int wm = w >> 1, wn = w & 1;
  const int lr = l & 15, lg = l >> 4;
  const int xorv = (l & 7) << 4;
  const int brow = blockIdx.y * 128;
  const int bcol = blockIdx.x * 128;
  const int src_chunk = (l & 7) ^ (l >> 3);
  const int rl = w * 8 + (l >> 3);

  f32x4 acc[4][4];
#pragma unroll
  for (int i = 0; i < 4; ++i)
#pragma unroll
    for (int j = 0; j < 4; ++j) acc[i][j] = (f32x4){0.f, 0.f, 0.f, 0.f};

  const char* Ag = (const char*)A;
  const char* Bg = (const char*)B;
  const int nkt = K >> 6;
  for (int kt = 0; kt < nkt; ++kt) {
    __syncthreads();
    const size_t kb = (size_t)kt * 128 + src_chunk * 16;
#pragma unroll
    for (int it = 0; it < 4; ++it)
      gload16(Ag + (size_t)(brow + it * 32 + rl) * (size_t)(K * 2) + kb,
              &As[(it * 32 + w * 8) * 64]);
#pragma unroll
    for (int it = 0; it < 4; ++it)
      gload16(Bg + (size_t)(bcol + it * 32 + rl) * (size_t)(K * 2) + kb,
              &Bs[(it * 32 + w * 8) * 64]);
    __syncthreads();

    bf16x8 af[4][2], bfr[4][2];
#pragma unroll
    for (int mi = 0; mi < 4; ++mi)
#pragma unroll
      for (int ks = 0; ks < 2; ++ks) {
        int row = wm * 64 + mi * 16 + lr;
        af[mi][ks] = *(const bf16x8*)((const char*)As + row * 128 + ((ks * 64 + lg * 16) ^ xorv));
      }
#pragma unroll
    for (int ni = 0; ni < 4; ++ni)
#pragma unroll
      for (int ks = 0; ks < 2; ++ks) {
        int row = wn * 64 + ni * 16 + lr;
        bfr[ni][ks] = *(const bf16x8*)((const char*)Bs + row * 128 + ((ks * 64 + lg * 16) ^ xorv));
      }
#pragma unroll
    for (int ks = 0; ks < 2; ++ks)
#pragma unroll
      for (int mi = 0; mi < 4; ++mi)
#pragma unroll
        for (int ni = 0; ni < 4; ++ni)
          acc[mi][ni] = __builtin_amdgcn_mfma_f32_16x16x32_bf16(
              af[mi][ks], bfr[ni][ks], acc[mi][ni], 0, 0, 0);
  }

  const float scale = alpha[bcol >> ashift];
#pragma unroll
  for (int mi = 0; mi < 4; ++mi)
#pragma unroll
    for (int ni = 0; ni < 4; ++ni)
#pragma unroll
      for (int r = 0; r < 4; ++r) {
        int row = brow + wm * 64 + mi * 16 + lg * 4 + r;
        int col = bcol + wn * 64 + ni * 16 + lr;
        float vv = acc[mi][ni][r] * scale;
        if (RES)
          ((float*)Cout)[(size_t)row * N + col] = res[(size_t)row * N + col] + vv;
        else
          ((u16*)Cout)[(size_t)row * N + col] = f2bf(vv);
      }
}

// ---------------------------------------------------------------------------
// Causal flash attention + act_quant epilogue.
// Block (p, h): q-tiles p and 31-p (68 k-iters for every block -> balanced).
// QBLK=128 (4 waves x 32 q-rows), KVBLK=64. Double-buffered K/V staging with
// raw s_barrier + vmcnt(4) (prefetch tile kt+1 under compute of kt).
// ---------------------------------------------------------------------------
__global__ __launch_bounds__(256) void attn_kernel(
    const u16* __restrict__ QKV, const u16* __restrict__ Vt, u16* __restrict__ Y) {
  __shared__ u16 Ks[2][64 * 64];  // [k-token 64][d 64] swizzled
  __shared__ u16 Vs[2][64 * 64];  // [d 64][k-token 64] swizzled
  __shared__ u16 Ps[4][32 * 64];

  const int tid = threadIdx.x;
  const int l = tid & 63, w = tid >> 6;
  const int lr = l & 15, lg = l >> 4;
  const int xorv = (l & 7) << 4;
  const int p = blockIdx.x;  // pair index 0..15
  const int h = blockIdx.y;
  const int src_chunk = (l & 7) ^ (l >> 3);
  const int rl = w * 8 + (l >> 3);

#pragma unroll 1
  for (int pass = 0; pass < 2; ++pass) {
    const int qt = pass ? (31 - p) : p;
    const int qrow0 = qt * 128 + w * 32;
    const int nkt = 2 * qt + 2;

    // Q fragments
    bf16x8 qf[2][2];
#pragma unroll
    for (int mi = 0; mi < 2; ++mi)
#pragma unroll
      for (int ks = 0; ks < 2; ++ks)
        qf[mi][ks] = __builtin_bit_cast(
            bf16x8, *(const u16x8*)(QKV + (size_t)(qrow0 + mi * 16 + lr) * 3072 +
                                    h * 64 + ks * 32 + lg * 8));

    f32x4 O[2][4];
#pragma unroll
    for (int mi = 0; mi < 2; ++mi)
#pragma unroll
      for (int ni = 0; ni < 4; ++ni) O[mi][ni] = (f32x4){0.f, 0.f, 0.f, 0.f};
    float m[2][4], lsum[2][4];
#pragma unroll
    for (int mi = 0; mi < 2; ++mi)
#pragma unroll
      for (int r = 0; r < 4; ++r) { m[mi][r] = -3e38f; lsum[mi][r] = 0.f; }

    auto STAGE = [&](int buf, int kt) {
#pragma unroll
      for (int it = 0; it < 2; ++it) {
        int krow = kt * 64 + it * 32 + rl;  // token index (per-lane)
        gload16((const char*)QKV + ((size_t)krow * 3072 + 1024 + h * 64) * 2 + src_chunk * 16,
                &Ks[buf][(it * 32 + w * 8) * 64]);
        int drow = it * 32 + rl;  // head-dim index (per-lane)
        gload16((const char*)Vt + (((size_t)h * 64 + drow) * 4096 + kt * 64) * 2 + src_chunk * 16,
                &Vs[buf][(it * 32 + w * 8) * 64]);
      }
    };

    STAGE(0, 0);  // prologue
#pragma unroll 1
    for (int kt = 0; kt < nkt; ++kt) {
      const int cur = kt & 1;
      if (kt + 1 < nkt) {
        STAGE(cur ^ 1, kt + 1);  // prefetch next tile into other buffer
        asm volatile("s_waitcnt vmcnt(4)" ::: "memory");  // current tile's 4 done
      } else {
        asm volatile("s_waitcnt vmcnt(0)" ::: "memory");
      }
      __builtin_amdgcn_s_barrier();
      __builtin_amdgcn_sched_barrier(0);

      const char* kbase = (const char*)&Ks[cur][0];
      const char* vbase = (const char*)&Vs[cur][0];

      // S[mi][ni] = Q @ K^T
      f32x4 S[2][4];
#pragma unroll
      for (int ni = 0; ni < 4; ++ni) {
        bf16x8 kf[2];
#pragma unroll
        for (int ks = 0; ks < 2; ++ks)
          kf[ks] = *(const bf16x8*)(kbase + (ni * 16 + lr) * 128 +
                                    ((ks * 64 + lg * 16) ^ xorv));
#pragma unroll
        for (int mi = 0; mi < 2; ++mi) {
          S[mi][ni] = (f32x4){0.f, 0.f, 0.f, 0.f};
#pragma unroll
          for (int ks = 0; ks < 2; ++ks)
            S[mi][ni] = __builtin_amdgcn_mfma_f32_16x16x32_bf16(qf[mi][ks], kf[ks],
                                                                S[mi][ni], 0, 0, 0);
        }
      }

      // scale + causal mask (only diagonal-touching tiles)
      const bool diag = (kt >= 2 * qt);
#pragma unroll
      for (int mi = 0; mi < 2; ++mi)
#pragma unroll
        for (int ni = 0; ni < 4; ++ni)
#pragma unroll
          for (int r = 0; r < 4; ++r) {
            float s = S[mi][ni][r] * 0.125f;
            if (diag && (kt * 64 + ni * 16 + lr) > (qrow0 + mi * 16 + lg * 4 + r)) s = -1e30f;
            S[mi][ni][r] = s;
          }

      // online softmax per (mi, r); row lives on the 16 lanes sharing lg
#pragma unroll
      for (int mi = 0; mi < 2; ++mi)
#pragma unroll
        for (int r = 0; r < 4; ++r) {
          float nm = fmaxf(fmaxf(S[mi][0][r], S[mi][1][r]), fmaxf(S[mi][2][r], S[mi][3][r]));
#pragma unroll
          for (int off = 1; off <= 8; off <<= 1) nm = fmaxf(nm, __shfl_xor(nm, off));
          float mn = fmaxf(m[mi][r], nm);
          float fac = __expf(m[mi][r] - mn);
          m[mi][r] = mn;
          float rs = 0.f;
#pragma unroll
          for (int ni = 0; ni < 4; ++ni) {
            float pv = __expf(S[mi][ni][r] - mn);
            S[mi][ni][r] = pv;  // S now holds P
            rs += pv;
          }
#pragma unroll
          for (int off = 1; off <= 8; off <<= 1) rs += __shfl_xor(rs, off);
          lsum[mi][r] = lsum[mi][r] * fac + rs;
#pragma unroll
          for (int ni = 0; ni < 4; ++ni) O[mi][ni][r] *= fac;
        }

      // P -> per-wave LDS (swizzled) -> A-frags
#pragma unroll
      for (int mi = 0; mi < 2; ++mi)
#pragma unroll
        for (int ni = 0; ni < 4; ++ni)
#pragma unroll
          for (int r = 0; r < 4; ++r) {
            int prow = mi * 16 + lg * 4 + r, pcol = ni * 16 + lr;
            *(u16*)((char*)&Ps[w][0] + prow * 128 + ((pcol * 2) ^ ((prow & 7) << 4))) =
                f2bf(S[mi][ni][r]);
          }
      bf16x8 pa[2][2];
#pragma unroll
      for (int mi = 0; mi < 2; ++mi)
#pragma unroll
        for (int ks = 0; ks < 2; ++ks)
          pa[mi][ks] = *(const bf16x8*)((const char*)&Ps[w][0] + (mi * 16 + lr) * 128 +
                                        ((ks * 64 + lg * 16) ^ xorv));

      // O += P @ V
#pragma unroll
      for (int ni = 0; ni < 4; ++ni) {
        bf16x8 vf[2];
#pragma unroll
        for (int ks = 0; ks < 2; ++ks)
          vf[ks] = *(const bf16x8*)(vbase + (ni * 16 + lr) * 128 +
                                    ((ks * 64 + lg * 16) ^ xorv));
#pragma unroll
        for (int mi = 0; mi < 2; ++mi)
#pragma unroll
          for (int ks = 0; ks < 2; ++ks)
            O[mi][ni] = __builtin_amdgcn_mfma_f32_16x16x32_bf16(pa[mi][ks], vf[ks],
                                                                O[mi][ni], 0, 0, 0);
      }
      asm volatile("" ::: "memory");
      __builtin_amdgcn_s_barrier();  // protect buf before next STAGE overwrites
    }

    // epilogue: normalize + act_quant (group of 64 = this head's dims)
#pragma unroll
    for (int mi = 0; mi < 2; ++mi) {
      float o[4][4];
#pragma unroll
      for (int ni = 0; ni < 4; ++ni)
#pragma unroll
        for (int r = 0; r < 4; ++r) o[ni][r] = O[mi][ni][r] / lsum[mi][r];
#pragma unroll
      for (int r = 0; r < 4; ++r) {
        float gm = fmaxf(fmaxf(fabsf(o[0][r]), fabsf(o[1][r])),
                         fmaxf(fabsf(o[2][r]), fabsf(o[3][r])));
#pragma unroll
        for (int off = 1; off <= 8; off <<= 1) gm = fmaxf(gm, __shfl_xor(gm, off));
        float s = fmaxf(gm, 1e-5f) / 127.0f;
#pragma unroll
        for (int ni = 0; ni < 4; ++ni)
          o[ni][r] = fminf(fmaxf(rintf(o[ni][r] / s), -127.f), 127.f) * s;
      }
#pragma unroll
      for (int ni = 0; ni < 4; ++ni)
#pragma unroll
        for (int r = 0; r < 4; ++r)
          Y[(size_t)(qrow0 + mi * 16 + lg * 4 + r) * 1024 + h * 64 + ni * 16 + lr] =
              f2bf(o[ni][r]);
    }
  }
}

// ---------------------------------------------------------------------------
extern "C" void kernel_launch(void* const* d_in, const int* in_sizes, int n_in,
                              void* d_out, int out_size, void* d_ws, size_t ws_size,
                              hipStream_t stream) {
  const float* x  = (const float*)d_in[0];
  const float* wq = (const float*)d_in[1];
  const float* wk = (const float*)d_in[2];
  const float* wv = (const float*)d_in[3];
  const float* wo = (const float*)d_in[4];
  const float* w1 = (const float*)d_in[5];
  const float* w2 = (const float*)d_in[6];
  const float* w3 = (const float*)d_in[7];
  const float* g1 = (const float*)d_in[8];
  const float* g2 = (const float*)d_in[9];

  char* ws = (char*)d_ws;
  const size_t MB = 1024 * 1024;
  u16* sWq   = (u16*)(ws + 0 * MB);
  u16* sWk   = (u16*)(ws + 2 * MB);
  u16* sWv   = (u16*)(ws + 4 * MB);
  u16* sWo   = (u16*)(ws + 6 * MB);
  u16* sW1   = (u16*)(ws + 8 * MB);    // w1|w2 contiguous -> fused [8192,1024]
  u16* sW2   = (u16*)(ws + 16 * MB);
  u16* sW3   = (u16*)(ws + 24 * MB);
  float* partial = (float*)(ws + 32 * MB);
  float* alphas  = (float*)(ws + 32 * MB + 16384);
  u16* Vt    = (u16*)(ws + 33 * MB);   // [16][64][4096], dead before x1 written
  float* x1  = (float*)(ws + 33 * MB); // fp32 [4096,1024] (after attn)
  u16* hq    = (u16*)(ws + 49 * MB);   // bf16 [4096,1024]
  u16* zq    = (u16*)(ws + 49 * MB);   // reuses hq slot (hq dead by silu)
  u16* qkv   = (u16*)(ws + 57 * MB);   // bf16 [4096,3072]
  u16* yb    = (u16*)(ws + 81 * MB);   // bf16 [4096,1024]
  u16* y1y2  = (u16*)(ws + 57 * MB);   // bf16 [4096,8192] (qkv,yb dead)

  // weight prep
  convert_sign<<<256, 256, 0, stream>>>(wq, sWq, partial + 0 * 256, 1048576 / 4);
  convert_sign<<<256, 256, 0, stream>>>(wk, sWk, partial + 1 * 256, 1048576 / 4);
  convert_sign<<<256, 256, 0, stream>>>(wv, sWv, partial + 2 * 256, 1048576 / 4);
  convert_sign<<<256, 256, 0, stream>>>(wo, sWo, partial + 3 * 256, 1048576 / 4);
  convert_sign<<<256, 256, 0, stream>>>(w1, sW1, partial + 4 * 256, 4194304 / 4);
  convert_sign<<<256, 256, 0, stream>>>(w2, sW2, partial + 5 * 256, 4194304 / 4);
  convert_sign<<<256, 256, 0, stream>>>(w3, sW3, partial + 6 * 256, 4194304 / 4);
  finalize_alpha<<<7, 256, 0, stream>>>(partial, alphas);

  // attention branch
  rmsnorm_quant<<<4096, 256, 0, stream>>>(x, g1, hq);
  gemm_bt<false><<<dim3(24, 32), 256, 0, stream>>>(hq, sWq, alphas, 10, nullptr,
                                                   qkv, 4096, 3072, 1024);
  transpose_v<<<dim3(64, 16), 256, 0, stream>>>(qkv, Vt);
  attn_kernel<<<dim3(16, 16), 256, 0, stream>>>(qkv, Vt, yb);
  gemm_bt<true><<<dim3(8, 32), 256, 0, stream>>>(yb, sWo, alphas + 3, 31, x,
                                                 x1, 4096, 1024, 1024);
  // FFN branch
  rmsnorm_quant<<<4096, 256, 0, stream>>>(x1, g2, hq);
  gemm_bt<false><<<dim3(64, 32), 256, 0, stream>>>(hq, sW1, alphas + 4, 12, nullptr,
                                                   y1y2, 4096, 8192, 1024);
  silu_mul_quant<<<16384, 256, 0, stream>>>(y1y2, zq);
  gemm_bt<true><<<dim3(8, 32), 256, 0, stream>>>(zq, sW3, alphas + 6, 31, x1,
                                                 (float*)d_out, 4096, 1024, 4096);
}

// Round 4
// 424.601 us; speedup vs baseline: 1.4471x; 1.1292x over previous
//
#include <hip/hip_runtime.h>
#include <math.h>

// ============================================================================
// BitNet transformer block, MI355X (gfx950).  Round 4.
// R3 -> R4: attention TLP fix. R3 had 256 blocks = 1 block/CU = 1 wave/SIMD
// (Occupancy 11.5%) -> latency-bound. Now QBLK=64 (4 waves x 16 q-rows),
// 64 q-tiles paired (p, 63-p): grid (32,16)=512 blocks, 2 blocks/CU,
// 8 waves/CU, every block exactly 65 k-iterations (deterministic balance).
// ws layout (MB = 2^20), peak 121 MB:
//   0..32    sign weights (wq@0,wk@2,wv@4,wo@6, w1@8,w2@16 (contig), w3@24)
//   32..33   alpha partials (7*256 f32); alphas (7 f32) at +16KB
//   33..49   Vt bf16 [16][64][4096] (live transpose->attn), then x1 fp32
//   49..57   hq bf16 (live rmsnorm->gemm), then zq bf16 (silu->w3 gemm)
//   57..81   qkv bf16 [4096,3072] (live ->attn); then y1y2 [4096,8192] 57..121
//   81..89   yb bf16 (attn->wo gemm), then overlaid by y1y2
// ============================================================================

typedef unsigned short u16;
typedef __attribute__((ext_vector_type(4))) float f32x4;
typedef __attribute__((ext_vector_type(4))) unsigned short u16x4;
typedef __attribute__((ext_vector_type(8))) unsigned short u16x8;
typedef __attribute__((ext_vector_type(8))) __bf16 bf16x8;

#define DEV static __device__ __forceinline__

DEV float bf2f(u16 u) { union { unsigned i; float f; } c; c.i = ((unsigned)u) << 16; return c.f; }
DEV u16 f2bf(float f) { __bf16 b = (__bf16)f; return __builtin_bit_cast(u16, b); }

DEV void gload16(const void* g, void* l) {
  __builtin_amdgcn_global_load_lds((__attribute__((address_space(1))) void*)g,
                                   (__attribute__((address_space(3))) void*)l,
                                   16, 0, 0);
}

// ---------------------------------------------------------------------------
// Weight prep: sign(w) -> bf16 {+1,-1,0}, block-partial sums of |w|.
// ---------------------------------------------------------------------------
__global__ __launch_bounds__(256) void convert_sign(
    const float* __restrict__ w, u16* __restrict__ sgn,
    float* __restrict__ partial, int n4) {
  __shared__ float red[4];
  float s = 0.f;
  for (int i = blockIdx.x * 256 + threadIdx.x; i < n4; i += 256 * 256) {
    f32x4 v = ((const f32x4*)w)[i];
    u16x4 o;
#pragma unroll
    for (int j = 0; j < 4; ++j) {
      float f = v[j];
      o[j] = f > 0.f ? (u16)0x3F80 : (f < 0.f ? (u16)0xBF80 : (u16)0);
      s += fabsf(f);
    }
    ((u16x4*)sgn)[i] = o;
  }
#pragma unroll
  for (int off = 32; off >= 1; off >>= 1) s += __shfl_xor(s, off);
  if ((threadIdx.x & 63) == 0) red[threadIdx.x >> 6] = s;
  __syncthreads();
  if (threadIdx.x == 0) partial[blockIdx.x] = red[0] + red[1] + red[2] + red[3];
}

__global__ __launch_bounds__(256) void finalize_alpha(
    const float* __restrict__ partial, float* __restrict__ alphas) {
  __shared__ float red[4];
  int wi = blockIdx.x;  // 0..6
  float v = partial[wi * 256 + threadIdx.x];
#pragma unroll
  for (int off = 32; off >= 1; off >>= 1) v += __shfl_xor(v, off);
  if ((threadIdx.x & 63) == 0) red[threadIdx.x >> 6] = v;
  __syncthreads();
  if (threadIdx.x == 0)
    alphas[wi] = (red[0] + red[1] + red[2] + red[3]) *
                 (wi < 4 ? (1.f / 1048576.f) : (1.f / 4194304.f));
}

// ---------------------------------------------------------------------------
// RMSNorm + act_quant (group 64). One block per row of 1024.
// ---------------------------------------------------------------------------
__global__ __launch_bounds__(256) void rmsnorm_quant(
    const float* __restrict__ x, const float* __restrict__ g, u16* __restrict__ out) {
  __shared__ float red[4];
  const int row = blockIdx.x, t = threadIdx.x;
  f32x4 v = ((const f32x4*)(x + (size_t)row * 1024))[t];
  float ss = v[0] * v[0] + v[1] * v[1] + v[2] * v[2] + v[3] * v[3];
#pragma unroll
  for (int off = 32; off >= 1; off >>= 1) ss += __shfl_xor(ss, off);
  if ((t & 63) == 0) red[t >> 6] = ss;
  __syncthreads();
  float tot = red[0] + red[1] + red[2] + red[3];
  float rinv = rsqrtf(tot * (1.f / 1024.f) + 1e-6f);
  f32x4 gg = ((const f32x4*)g)[t];
  float n[4];
#pragma unroll
  for (int j = 0; j < 4; ++j) n[j] = v[j] * rinv * gg[j];
  float gm = fmaxf(fmaxf(fabsf(n[0]), fabsf(n[1])), fmaxf(fabsf(n[2]), fabsf(n[3])));
#pragma unroll
  for (int off = 1; off <= 8; off <<= 1) gm = fmaxf(gm, __shfl_xor(gm, off));
  float s = fmaxf(gm, 1e-5f) / 127.0f;
  u16x4 o;
#pragma unroll
  for (int j = 0; j < 4; ++j) {
    float q = fminf(fmaxf(rintf(n[j] / s), -127.f), 127.f) * s;
    o[j] = f2bf(q);
  }
  ((u16x4*)out)[(size_t)row * 256 + t] = o;
}

// ---------------------------------------------------------------------------
// silu(y1)*y2 + act_quant. y1y2 fused [4096, 8192].
// ---------------------------------------------------------------------------
__global__ __launch_bounds__(256) void silu_mul_quant(
    const u16* __restrict__ y1y2, u16* __restrict__ zq) {
  size_t idx = (size_t)blockIdx.x * 1024 + threadIdx.x * 4;  // 0..16M
  size_t row = idx >> 12, c = idx & 4095;
  u16x4 a4 = *(const u16x4*)(y1y2 + row * 8192 + c);
  u16x4 b4 = *(const u16x4*)(y1y2 + row * 8192 + 4096 + c);
  float z[4];
#pragma unroll
  for (int j = 0; j < 4; ++j) {
    float a = bf2f(a4[j]);
    z[j] = a / (1.f + __expf(-a)) * bf2f(b4[j]);
  }
  float gm = fmaxf(fmaxf(fabsf(z[0]), fabsf(z[1])), fmaxf(fabsf(z[2]), fabsf(z[3])));
#pragma unroll
  for (int off = 1; off <= 8; off <<= 1) gm = fmaxf(gm, __shfl_xor(gm, off));
  float s = fmaxf(gm, 1e-5f) / 127.0f;
  u16x4 o;
#pragma unroll
  for (int j = 0; j < 4; ++j) {
    float q = fminf(fmaxf(rintf(z[j] / s), -127.f), 127.f) * s;
    o[j] = f2bf(q);
  }
  *(u16x4*)(zq + idx) = o;
}

// ---------------------------------------------------------------------------
// V transpose: qkv[:,2048+h*64 .. +63] -> Vt[h][d][t]  ([16][64][4096] bf16).
// ---------------------------------------------------------------------------
__global__ __launch_bounds__(256) void transpose_v(
    const u16* __restrict__ qkv, u16* __restrict__ Vt) {
  __shared__ u16 T[64][65];
  const int tt = blockIdx.x, h = blockIdx.y, tid = threadIdx.x;
#pragma unroll
  for (int i = 0; i < 2; ++i) {
    int idx = i * 2048 + tid * 8;
    int trow = idx >> 6, dcol = idx & 63;
    u16x8 v = *(const u16x8*)(qkv + (size_t)(tt * 64 + trow) * 3072 + 2048 + h * 64 + dcol);
#pragma unroll
    for (int j = 0; j < 8; ++j) T[dcol + j][trow] = v[j];
  }
  __syncthreads();
#pragma unroll
  for (int i = 0; i < 2; ++i) {
    int idx = i * 2048 + tid * 8;
    int drow = idx >> 6, tcol = idx & 63;
    u16x8 v;
#pragma unroll
    for (int j = 0; j < 8; ++j) v[j] = T[drow][tcol + j];
    *(u16x8*)(Vt + ((size_t)h * 64 + drow) * 4096 + tt * 64 + tcol) = v;
  }
}

// ---------------------------------------------------------------------------
// GEMM: C[M,N] = alpha[bcol>>ashift] * (A[M,K] @ B[N,K]^T) (+res).
// 128x128 tile, BK=64, 4 waves (2x2), global_load_lds w=16, XOR swizzle.
// ---------------------------------------------------------------------------
template <bool RES>
__global__ __launch_bounds__(256) void gemm_bt(
    const u16* __restrict__ A, const u16* __restrict__ B,
    const float* __restrict__ alpha, int ashift, const float* __restrict__ res,
    void* __restrict__ Cout, int M, int N, int K) {
  __shared__ u16 As[128 * 64];
  __shared__ u16 Bs[128 * 64];
  const int tid = threadIdx.x;
  const int l = tid & 63, w = tid >> 6;
  const int wm = w >> 1, wn = w & 1;
  const int lr = l & 15, lg = l >> 4;
  const int xorv = (l & 7) << 4;
  const int brow = blockIdx.y * 128;
  const int bcol = blockIdx.x * 128;
  const int src_chunk = (l & 7) ^ (l >> 3);
  const int rl = w * 8 + (l >> 3);

  f32x4 acc[4][4];
#pragma unroll
  for (int i = 0; i < 4; ++i)
#pragma unroll
    for (int j = 0; j < 4; ++j) acc[i][j] = (f32x4){0.f, 0.f, 0.f, 0.f};

  const char* Ag = (const char*)A;
  const char* Bg = (const char*)B;
  const int nkt = K >> 6;
  for (int kt = 0; kt < nkt; ++kt) {
    __syncthreads();
    const size_t kb = (size_t)kt * 128 + src_chunk * 16;
#pragma unroll
    for (int it = 0; it < 4; ++it)
      gload16(Ag + (size_t)(brow + it * 32 + rl) * (size_t)(K * 2) + kb,
              &As[(it * 32 + w * 8) * 64]);
#pragma unroll
    for (int it = 0; it < 4; ++it)
      gload16(Bg + (size_t)(bcol + it * 32 + rl) * (size_t)(K * 2) + kb,
              &Bs[(it * 32 + w * 8) * 64]);
    __syncthreads();

    bf16x8 af[4][2], bfr[4][2];
#pragma unroll
    for (int mi = 0; mi < 4; ++mi)
#pragma unroll
      for (int ks = 0; ks < 2; ++ks) {
        int row = wm * 64 + mi * 16 + lr;
        af[mi][ks] = *(const bf16x8*)((const char*)As + row * 128 + ((ks * 64 + lg * 16) ^ xorv));
      }
#pragma unroll
    for (int ni = 0; ni < 4; ++ni)
#pragma unroll
      for (int ks = 0; ks < 2; ++ks) {
        int row = wn * 64 + ni * 16 + lr;
        bfr[ni][ks] = *(const bf16x8*)((const char*)Bs + row * 128 + ((ks * 64 + lg * 16) ^ xorv));
      }
#pragma unroll
    for (int ks = 0; ks < 2; ++ks)
#pragma unroll
      for (int mi = 0; mi < 4; ++mi)
#pragma unroll
        for (int ni = 0; ni < 4; ++ni)
          acc[mi][ni] = __builtin_amdgcn_mfma_f32_16x16x32_bf16(
              af[mi][ks], bfr[ni][ks], acc[mi][ni], 0, 0, 0);
  }

  const float scale = alpha[bcol >> ashift];
#pragma unroll
  for (int mi = 0; mi < 4; ++mi)
#pragma unroll
    for (int ni = 0; ni < 4; ++ni)
#pragma unroll
      for (int r = 0; r < 4; ++r) {
        int row = brow + wm * 64 + mi * 16 + lg * 4 + r;
        int col = bcol + wn * 64 + ni * 16 + lr;
        float vv = acc[mi][ni][r] * scale;
        if (RES)
          ((float*)Cout)[(size_t)row * N + col] = res[(size_t)row * N + col] + vv;
        else
          ((u16*)Cout)[(size_t)row * N + col] = f2bf(vv);
      }
}

// ---------------------------------------------------------------------------
// Causal flash attention + act_quant epilogue.
// Block (p, h): q-tiles qt=p and qt=63-p of 64 rows (65 k-iters per block,
// deterministic). 4 waves x 16 q-rows. Grid (32,16)=512 -> 2 blocks/CU,
// 8 waves/CU. Double-buffered K/V staging, raw s_barrier + vmcnt(4).
// ---------------------------------------------------------------------------
__global__ __launch_bounds__(256) void attn_kernel(
    const u16* __restrict__ QKV, const u16* __restrict__ Vt, u16* __restrict__ Y) {
  __shared__ u16 Ks[2][64 * 64];  // [k-token 64][d 64] swizzled
  __shared__ u16 Vs[2][64 * 64];  // [d 64][k-token 64] swizzled
  __shared__ u16 Ps[4][16 * 64];

  const int tid = threadIdx.x;
  const int l = tid & 63, w = tid >> 6;
  const int lr = l & 15, lg = l >> 4;
  const int xorv = (l & 7) << 4;
  const int p = blockIdx.x;  // pair index 0..31
  const int h = blockIdx.y;
  const int src_chunk = (l & 7) ^ (l >> 3);
  const int rl = w * 8 + (l >> 3);

#pragma unroll 1
  for (int pass = 0; pass < 2; ++pass) {
    const int qt = pass ? (63 - p) : p;   // 64-row q-tile index
    const int qrow0 = qt * 64 + w * 16;   // this wave's first q row
    const int nkt = qt + 1;

    // Q fragments (row = qrow0 + lr)
    bf16x8 qf[2];
#pragma unroll
    for (int ks = 0; ks < 2; ++ks)
      qf[ks] = __builtin_bit_cast(
          bf16x8, *(const u16x8*)(QKV + (size_t)(qrow0 + lr) * 3072 +
                                  h * 64 + ks * 32 + lg * 8));

    f32x4 O[4];
#pragma unroll
    for (int ni = 0; ni < 4; ++ni) O[ni] = (f32x4){0.f, 0.f, 0.f, 0.f};
    float m[4], lsum[4];
#pragma unroll
    for (int r = 0; r < 4; ++r) { m[r] = -3e38f; lsum[r] = 0.f; }

    auto STAGE = [&](int buf, int kt) {
#pragma unroll
      for (int it = 0; it < 2; ++it) {
        int krow = kt * 64 + it * 32 + rl;  // token index (per-lane)
        gload16((const char*)QKV + ((size_t)krow * 3072 + 1024 + h * 64) * 2 + src_chunk * 16,
                &Ks[buf][(it * 32 + w * 8) * 64]);
        int drow = it * 32 + rl;  // head-dim index (per-lane)
        gload16((const char*)Vt + (((size_t)h * 64 + drow) * 4096 + kt * 64) * 2 + src_chunk * 16,
                &Vs[buf][(it * 32 + w * 8) * 64]);
      }
    };

    STAGE(0, 0);  // prologue
#pragma unroll 1
    for (int kt = 0; kt < nkt; ++kt) {
      const int cur = kt & 1;
      if (kt + 1 < nkt) {
        STAGE(cur ^ 1, kt + 1);  // prefetch next tile into other buffer
        asm volatile("s_waitcnt vmcnt(4)" ::: "memory");  // current tile's 4 done
      } else {
        asm volatile("s_waitcnt vmcnt(0)" ::: "memory");
      }
      __builtin_amdgcn_s_barrier();
      __builtin_amdgcn_sched_barrier(0);

      const char* kbase = (const char*)&Ks[cur][0];
      const char* vbase = (const char*)&Vs[cur][0];

      // S[ni] = Q @ K^T
      f32x4 S[4];
#pragma unroll
      for (int ni = 0; ni < 4; ++ni) {
        S[ni] = (f32x4){0.f, 0.f, 0.f, 0.f};
#pragma unroll
        for (int ks = 0; ks < 2; ++ks) {
          bf16x8 kf = *(const bf16x8*)(kbase + (ni * 16 + lr) * 128 +
                                       ((ks * 64 + lg * 16) ^ xorv));
          S[ni] = __builtin_amdgcn_mfma_f32_16x16x32_bf16(qf[ks], kf, S[ni], 0, 0, 0);
        }
      }

      // scale + causal mask (diag tile = last)
      const bool diag = (kt == qt);
#pragma unroll
      for (int ni = 0; ni < 4; ++ni)
#pragma unroll
        for (int r = 0; r < 4; ++r) {
          float s = S[ni][r] * 0.125f;
          if (diag && (ni * 16 + lr) > (w * 16 + lg * 4 + r)) s = -1e30f;
          S[ni][r] = s;
        }

      // online softmax per r; row lives on 16 lanes sharing lg
#pragma unroll
      for (int r = 0; r < 4; ++r) {
        float nm = fmaxf(fmaxf(S[0][r], S[1][r]), fmaxf(S[2][r], S[3][r]));
#pragma unroll
        for (int off = 1; off <= 8; off <<= 1) nm = fmaxf(nm, __shfl_xor(nm, off));
        float mn = fmaxf(m[r], nm);
        float fac = __expf(m[r] - mn);
        m[r] = mn;
        float rs = 0.f;
#pragma unroll
        for (int ni = 0; ni < 4; ++ni) {
          float pv = __expf(S[ni][r] - mn);
          S[ni][r] = pv;  // S now holds P
          rs += pv;
        }
#pragma unroll
        for (int off = 1; off <= 8; off <<= 1) rs += __shfl_xor(rs, off);
        lsum[r] = lsum[r] * fac + rs;
#pragma unroll
        for (int ni = 0; ni < 4; ++ni) O[ni][r] *= fac;
      }

      // P -> per-wave LDS (swizzled) -> A-frags
#pragma unroll
      for (int ni = 0; ni < 4; ++ni)
#pragma unroll
        for (int r = 0; r < 4; ++r) {
          int prow = lg * 4 + r, pcol = ni * 16 + lr;
          *(u16*)((char*)&Ps[w][0] + prow * 128 + ((pcol * 2) ^ ((prow & 7) << 4))) =
              f2bf(S[ni][r]);
        }
      bf16x8 pa[2];
#pragma unroll
      for (int ks = 0; ks < 2; ++ks)
        pa[ks] = *(const bf16x8*)((const char*)&Ps[w][0] + lr * 128 +
                                  ((ks * 64 + lg * 16) ^ xorv));

      // O += P @ V
#pragma unroll
      for (int ni = 0; ni < 4; ++ni) {
#pragma unroll
        for (int ks = 0; ks < 2; ++ks) {
          bf16x8 vf = *(const bf16x8*)(vbase + (ni * 16 + lr) * 128 +
                                       ((ks * 64 + lg * 16) ^ xorv));
          O[ni] = __builtin_amdgcn_mfma_f32_16x16x32_bf16(pa[ks], vf, O[ni], 0, 0, 0);
        }
      }
      asm volatile("" ::: "memory");
      __builtin_amdgcn_s_barrier();  // protect buf before next STAGE overwrites
    }

    // epilogue: normalize + act_quant (group of 64 = this head's dims)
    float o[4][4];
#pragma unroll
    for (int ni = 0; ni < 4; ++ni)
#pragma unroll
      for (int r = 0; r < 4; ++r) o[ni][r] = O[ni][r] / lsum[r];
#pragma unroll
    for (int r = 0; r < 4; ++r) {
      float gm = fmaxf(fmaxf(fabsf(o[0][r]), fabsf(o[1][r])),
                       fmaxf(fabsf(o[2][r]), fabsf(o[3][r])));
#pragma unroll
      for (int off = 1; off <= 8; off <<= 1) gm = fmaxf(gm, __shfl_xor(gm, off));
      float s = fmaxf(gm, 1e-5f) / 127.0f;
#pragma unroll
      for (int ni = 0; ni < 4; ++ni)
        o[ni][r] = fminf(fmaxf(rintf(o[ni][r] / s), -127.f), 127.f) * s;
    }
#pragma unroll
    for (int ni = 0; ni < 4; ++ni)
#pragma unroll
      for (int r = 0; r < 4; ++r)
        Y[(size_t)(qt * 64 + w * 16 + lg * 4 + r) * 1024 + h * 64 + ni * 16 + lr] =
            f2bf(o[ni][r]);
  }
}

// ---------------------------------------------------------------------------
extern "C" void kernel_launch(void* const* d_in, const int* in_sizes, int n_in,
                              void* d_out, int out_size, void* d_ws, size_t ws_size,
                              hipStream_t stream) {
  const float* x  = (const float*)d_in[0];
  const float* wq = (const float*)d_in[1];
  const float* wk = (const float*)d_in[2];
  const float* wv = (const float*)d_in[3];
  const float* wo = (const float*)d_in[4];
  const float* w1 = (const float*)d_in[5];
  const float* w2 = (const float*)d_in[6];
  const float* w3 = (const float*)d_in[7];
  const float* g1 = (const float*)d_in[8];
  const float* g2 = (const float*)d_in[9];

  char* ws = (char*)d_ws;
  const size_t MB = 1024 * 1024;
  u16* sWq   = (u16*)(ws + 0 * MB);
  u16* sWk   = (u16*)(ws + 2 * MB);
  u16* sWv   = (u16*)(ws + 4 * MB);
  u16* sWo   = (u16*)(ws + 6 * MB);
  u16* sW1   = (u16*)(ws + 8 * MB);    // w1|w2 contiguous -> fused [8192,1024]
  u16* sW2   = (u16*)(ws + 16 * MB);
  u16* sW3   = (u16*)(ws + 24 * MB);
  float* partial = (float*)(ws + 32 * MB);
  float* alphas  = (float*)(ws + 32 * MB + 16384);
  u16* Vt    = (u16*)(ws + 33 * MB);   // [16][64][4096], dead before x1 written
  float* x1  = (float*)(ws + 33 * MB); // fp32 [4096,1024] (after attn)
  u16* hq    = (u16*)(ws + 49 * MB);   // bf16 [4096,1024]
  u16* zq    = (u16*)(ws + 49 * MB);   // reuses hq slot (hq dead by silu)
  u16* qkv   = (u16*)(ws + 57 * MB);   // bf16 [4096,3072]
  u16* yb    = (u16*)(ws + 81 * MB);   // bf16 [4096,1024]
  u16* y1y2  = (u16*)(ws + 57 * MB);   // bf16 [4096,8192] (qkv,yb dead)

  // weight prep
  convert_sign<<<256, 256, 0, stream>>>(wq, sWq, partial + 0 * 256, 1048576 / 4);
  convert_sign<<<256, 256, 0, stream>>>(wk, sWk, partial + 1 * 256, 1048576 / 4);
  convert_sign<<<256, 256, 0, stream>>>(wv, sWv, partial + 2 * 256, 1048576 / 4);
  convert_sign<<<256, 256, 0, stream>>>(wo, sWo, partial + 3 * 256, 1048576 / 4);
  convert_sign<<<256, 256, 0, stream>>>(w1, sW1, partial + 4 * 256, 4194304 / 4);
  convert_sign<<<256, 256, 0, stream>>>(w2, sW2, partial + 5 * 256, 4194304 / 4);
  convert_sign<<<256, 256, 0, stream>>>(w3, sW3, partial + 6 * 256, 4194304 / 4);
  finalize_alpha<<<7, 256, 0, stream>>>(partial, alphas);

  // attention branch
  rmsnorm_quant<<<4096, 256, 0, stream>>>(x, g1, hq);
  gemm_bt<false><<<dim3(24, 32), 256, 0, stream>>>(hq, sWq, alphas, 10, nullptr,
                                                   qkv, 4096, 3072, 1024);
  transpose_v<<<dim3(64, 16), 256, 0, stream>>>(qkv, Vt);
  attn_kernel<<<dim3(32, 16), 256, 0, stream>>>(qkv, Vt, yb);
  gemm_bt<true><<<dim3(8, 32), 256, 0, stream>>>(yb, sWo, alphas + 3, 31, x,
                                                 x1, 4096, 1024, 1024);
  // FFN branch
  rmsnorm_quant<<<4096, 256, 0, stream>>>(x1, g2, hq);
  gemm_bt<false><<<dim3(64, 32), 256, 0, stream>>>(hq, sW1, alphas + 4, 12, nullptr,
                                                   y1y2, 4096, 8192, 1024);
  silu_mul_quant<<<16384, 256, 0, stream>>>(y1y2, zq);
  gemm_bt<true><<<dim3(8, 32), 256, 0, stream>>>(zq, sW3, alphas + 6, 31, x1,
                                                 (float*)d_out, 4096, 1024, 4096);
}

// Round 5
// 364.473 us; speedup vs baseline: 1.6858x; 1.1650x over previous
//
#include <hip/hip_runtime.h>
#include <math.h>

// ============================================================================
// BitNet transformer block, MI355X (gfx950).  Round 5.
// R4 -> R5:
//  (a) attn: swapped QK^T (S^T = mfma(K,Q)) -> each lane owns one q-row's
//      full 64 tokens; softmax reduce = in-lane + 2 shuffles (was 32);
//      P^T round-trip = 4x ds_write_b64 (was 16 scalar); PV = mfma(V^T,P^T).
//  (b) gemm_bt templated BM (128|64): wo/w3 use BM=64 -> 512 blocks, 2/CU.
// ws layout (MB = 2^20), peak 121 MB:
//   0..32    sign weights (wq@0,wk@2,wv@4,wo@6, w1@8,w2@16 (contig), w3@24)
//   32..33   alpha partials (7*256 f32); alphas (7 f32) at +16KB
//   33..49   Vt bf16 [16][64][4096] (live transpose->attn), then x1 fp32
//   49..57   hq bf16 (live rmsnorm->gemm), then zq bf16 (silu->w3 gemm)
//   57..81   qkv bf16 [4096,3072] (live ->attn); then y1y2 [4096,8192] 57..121
//   81..89   yb bf16 (attn->wo gemm), then overlaid by y1y2
// ============================================================================

typedef unsigned short u16;
typedef __attribute__((ext_vector_type(4))) float f32x4;
typedef __attribute__((ext_vector_type(4))) unsigned short u16x4;
typedef __attribute__((ext_vector_type(8))) unsigned short u16x8;
typedef __attribute__((ext_vector_type(8))) __bf16 bf16x8;

#define DEV static __device__ __forceinline__

DEV float bf2f(u16 u) { union { unsigned i; float f; } c; c.i = ((unsigned)u) << 16; return c.f; }
DEV u16 f2bf(float f) { __bf16 b = (__bf16)f; return __builtin_bit_cast(u16, b); }

DEV void gload16(const void* g, void* l) {
  __builtin_amdgcn_global_load_lds((__attribute__((address_space(1))) void*)g,
                                   (__attribute__((address_space(3))) void*)l,
                                   16, 0, 0);
}

// ---------------------------------------------------------------------------
// Weight prep: sign(w) -> bf16 {+1,-1,0}, block-partial sums of |w|.
// ---------------------------------------------------------------------------
__global__ __launch_bounds__(256) void convert_sign(
    const float* __restrict__ w, u16* __restrict__ sgn,
    float* __restrict__ partial, int n4) {
  __shared__ float red[4];
  float s = 0.f;
  for (int i = blockIdx.x * 256 + threadIdx.x; i < n4; i += 256 * 256) {
    f32x4 v = ((const f32x4*)w)[i];
    u16x4 o;
#pragma unroll
    for (int j = 0; j < 4; ++j) {
      float f = v[j];
      o[j] = f > 0.f ? (u16)0x3F80 : (f < 0.f ? (u16)0xBF80 : (u16)0);
      s += fabsf(f);
    }
    ((u16x4*)sgn)[i] = o;
  }
#pragma unroll
  for (int off = 32; off >= 1; off >>= 1) s += __shfl_xor(s, off);
  if ((threadIdx.x & 63) == 0) red[threadIdx.x >> 6] = s;
  __syncthreads();
  if (threadIdx.x == 0) partial[blockIdx.x] = red[0] + red[1] + red[2] + red[3];
}

__global__ __launch_bounds__(256) void finalize_alpha(
    const float* __restrict__ partial, float* __restrict__ alphas) {
  __shared__ float red[4];
  int wi = blockIdx.x;  // 0..6
  float v = partial[wi * 256 + threadIdx.x];
#pragma unroll
  for (int off = 32; off >= 1; off >>= 1) v += __shfl_xor(v, off);
  if ((threadIdx.x & 63) == 0) red[threadIdx.x >> 6] = v;
  __syncthreads();
  if (threadIdx.x == 0)
    alphas[wi] = (red[0] + red[1] + red[2] + red[3]) *
                 (wi < 4 ? (1.f / 1048576.f) : (1.f / 4194304.f));
}

// ---------------------------------------------------------------------------
// RMSNorm + act_quant (group 64). One block per row of 1024.
// ---------------------------------------------------------------------------
__global__ __launch_bounds__(256) void rmsnorm_quant(
    const float* __restrict__ x, const float* __restrict__ g, u16* __restrict__ out) {
  __shared__ float red[4];
  const int row = blockIdx.x, t = threadIdx.x;
  f32x4 v = ((const f32x4*)(x + (size_t)row * 1024))[t];
  float ss = v[0] * v[0] + v[1] * v[1] + v[2] * v[2] + v[3] * v[3];
#pragma unroll
  for (int off = 32; off >= 1; off >>= 1) ss += __shfl_xor(ss, off);
  if ((t & 63) == 0) red[t >> 6] = ss;
  __syncthreads();
  float tot = red[0] + red[1] + red[2] + red[3];
  float rinv = rsqrtf(tot * (1.f / 1024.f) + 1e-6f);
  f32x4 gg = ((const f32x4*)g)[t];
  float n[4];
#pragma unroll
  for (int j = 0; j < 4; ++j) n[j] = v[j] * rinv * gg[j];
  float gm = fmaxf(fmaxf(fabsf(n[0]), fabsf(n[1])), fmaxf(fabsf(n[2]), fabsf(n[3])));
#pragma unroll
  for (int off = 1; off <= 8; off <<= 1) gm = fmaxf(gm, __shfl_xor(gm, off));
  float s = fmaxf(gm, 1e-5f) / 127.0f;
  u16x4 o;
#pragma unroll
  for (int j = 0; j < 4; ++j) {
    float q = fminf(fmaxf(rintf(n[j] / s), -127.f), 127.f) * s;
    o[j] = f2bf(q);
  }
  ((u16x4*)out)[(size_t)row * 256 + t] = o;
}

// ---------------------------------------------------------------------------
// silu(y1)*y2 + act_quant. y1y2 fused [4096, 8192].
// ---------------------------------------------------------------------------
__global__ __launch_bounds__(256) void silu_mul_quant(
    const u16* __restrict__ y1y2, u16* __restrict__ zq) {
  size_t idx = (size_t)blockIdx.x * 1024 + threadIdx.x * 4;  // 0..16M
  size_t row = idx >> 12, c = idx & 4095;
  u16x4 a4 = *(const u16x4*)(y1y2 + row * 8192 + c);
  u16x4 b4 = *(const u16x4*)(y1y2 + row * 8192 + 4096 + c);
  float z[4];
#pragma unroll
  for (int j = 0; j < 4; ++j) {
    float a = bf2f(a4[j]);
    z[j] = a / (1.f + __expf(-a)) * bf2f(b4[j]);
  }
  float gm = fmaxf(fmaxf(fabsf(z[0]), fabsf(z[1])), fmaxf(fabsf(z[2]), fabsf(z[3])));
#pragma unroll
  for (int off = 1; off <= 8; off <<= 1) gm = fmaxf(gm, __shfl_xor(gm, off));
  float s = fmaxf(gm, 1e-5f) / 127.0f;
  u16x4 o;
#pragma unroll
  for (int j = 0; j < 4; ++j) {
    float q = fminf(fmaxf(rintf(z[j] / s), -127.f), 127.f) * s;
    o[j] = f2bf(q);
  }
  *(u16x4*)(zq + idx) = o;
}

// ---------------------------------------------------------------------------
// V transpose: qkv[:,2048+h*64 .. +63] -> Vt[h][d][t]  ([16][64][4096] bf16).
// ---------------------------------------------------------------------------
__global__ __launch_bounds__(256) void transpose_v(
    const u16* __restrict__ qkv, u16* __restrict__ Vt) {
  __shared__ u16 T[64][65];
  const int tt = blockIdx.x, h = blockIdx.y, tid = threadIdx.x;
#pragma unroll
  for (int i = 0; i < 2; ++i) {
    int idx = i * 2048 + tid * 8;
    int trow = idx >> 6, dcol = idx & 63;
    u16x8 v = *(const u16x8*)(qkv + (size_t)(tt * 64 + trow) * 3072 + 2048 + h * 64 + dcol);
#pragma unroll
    for (int j = 0; j < 8; ++j) T[dcol + j][trow] = v[j];
  }
  __syncthreads();
#pragma unroll
  for (int i = 0; i < 2; ++i) {
    int idx = i * 2048 + tid * 8;
    int drow = idx >> 6, tcol = idx & 63;
    u16x8 v;
#pragma unroll
    for (int j = 0; j < 8; ++j) v[j] = T[drow][tcol + j];
    *(u16x8*)(Vt + ((size_t)h * 64 + drow) * 4096 + tt * 64 + tcol) = v;
  }
}

// ---------------------------------------------------------------------------
// GEMM: C[M,N] = alpha[bcol>>ashift] * (A[M,K] @ B[N,K]^T) (+res).
// BMxN=128 tile (BM = 128 or 64), BK=64, 4 waves, global_load_lds w=16,
// XOR swizzle. BM=64 -> 2x the blocks for small-grid shapes (occupancy).
// ---------------------------------------------------------------------------
template <bool RES, int BM>
__global__ __launch_bounds__(256) void gemm_bt(
    const u16* __restrict__ A, const u16* __restrict__ B,
    const float* __restrict__ alpha, int ashift, const float* __restrict__ res,
    void* __restrict__ Cout, int M, int N, int K) {
  constexpr int NI = (BM == 128) ? 4 : 2;    // per-wave N fragments
  constexpr int WNE = (BM == 128) ? 64 : 32; // per-wave N extent
  __shared__ u16 As[BM * 64];
  __shared__ u16 Bs[128 * 64];
  const int tid = threadIdx.x;
  const int l = tid & 63, w = tid >> 6;
  const int wm = (BM == 128) ? (w >> 1) : 0;
  const int wn = (BM == 128) ? (w & 1) : w;
  const int lr = l & 15, lg = l >> 4;
  const int xorv = (l & 7) << 4;
  const int brow = blockIdx.y * BM;
  const int bcol = blockIdx.x * 128;
  const int src_chunk = (l & 7) ^ (l >> 3);
  const int rl = w * 8 + (l >> 3);

  f32x4 acc[4][NI];
#pragma unroll
  for (int i = 0; i < 4; ++i)
#pragma unroll
    for (int j = 0; j < NI; ++j) acc[i][j] = (f32x4){0.f, 0.f, 0.f, 0.f};

  const char* Ag = (const char*)A;
  const char* Bg = (const char*)B;
  const int nkt = K >> 6;
  for (int kt = 0; kt < nkt; ++kt) {
    __syncthreads();
    const size_t kb = (size_t)kt * 128 + src_chunk * 16;
#pragma unroll
    for (int it = 0; it < BM / 32; ++it)
      gload16(Ag + (size_t)(brow + it * 32 + rl) * (size_t)(K * 2) + kb,
              &As[(it * 32 + w * 8) * 64]);
#pragma unroll
    for (int it = 0; it < 4; ++it)
      gload16(Bg + (size_t)(bcol + it * 32 + rl) * (size_t)(K * 2) + kb,
              &Bs[(it * 32 + w * 8) * 64]);
    __syncthreads();

    bf16x8 af[4][2], bfr[NI][2];
#pragma unroll
    for (int mi = 0; mi < 4; ++mi)
#pragma unroll
      for (int ks = 0; ks < 2; ++ks) {
        int row = wm * 64 + mi * 16 + lr;
        af[mi][ks] = *(const bf16x8*)((const char*)As + row * 128 + ((ks * 64 + lg * 16) ^ xorv));
      }
#pragma unroll
    for (int ni = 0; ni < NI; ++ni)
#pragma unroll
      for (int ks = 0; ks < 2; ++ks) {
        int row = wn * WNE + ni * 16 + lr;
        bfr[ni][ks] = *(const bf16x8*)((const char*)Bs + row * 128 + ((ks * 64 + lg * 16) ^ xorv));
      }
#pragma unroll
    for (int ks = 0; ks < 2; ++ks)
#pragma unroll
      for (int mi = 0; mi < 4; ++mi)
#pragma unroll
        for (int ni = 0; ni < NI; ++ni)
          acc[mi][ni] = __builtin_amdgcn_mfma_f32_16x16x32_bf16(
              af[mi][ks], bfr[ni][ks], acc[mi][ni], 0, 0, 0);
  }

  const float scale = alpha[bcol >> ashift];
#pragma unroll
  for (int mi = 0; mi < 4; ++mi)
#pragma unroll
    for (int ni = 0; ni < NI; ++ni)
#pragma unroll
      for (int r = 0; r < 4; ++r) {
        int row = brow + wm * 64 + mi * 16 + lg * 4 + r;
        int col = bcol + wn * WNE + ni * 16 + lr;
        float vv = acc[mi][ni][r] * scale;
        if (RES)
          ((float*)Cout)[(size_t)row * N + col] = res[(size_t)row * N + col] + vv;
        else
          ((u16*)Cout)[(size_t)row * N + col] = f2bf(vv);
      }
}

// ---------------------------------------------------------------------------
// Causal flash attention + act_quant epilogue.  SWAPPED-OPERAND form:
// S^T = mfma(K,Q): lane l owns q-row (qrow0+lr); its 16 regs hold tokens
// ni*16+lg*4+r. Softmax: in-lane reduce + shfl_xor(16,32). P^T packed to LDS
// (4x ds_write_b64), PV: O^T = mfma(V^T, P^T). Block (p,h) does q-tiles p and
// 63-p (65 k-iters, deterministic balance); grid (32,16) -> 2 blocks/CU.
// ---------------------------------------------------------------------------
__global__ __launch_bounds__(256) void attn_kernel(
    const u16* __restrict__ QKV, const u16* __restrict__ Vt, u16* __restrict__ Y) {
  __shared__ u16 Ks[2][64 * 64];  // [k-token 64][d 64] swizzled
  __shared__ u16 Vs[2][64 * 64];  // [d 64][k-token 64] swizzled
  __shared__ u16 Ps[4][16 * 64];  // per-wave P^T as [q 16][token 64] swizzled

  const int tid = threadIdx.x;
  const int l = tid & 63, w = tid >> 6;
  const int lr = l & 15, lg = l >> 4;
  const int xorv = (l & 7) << 4;  // == (lr&7)<<4
  const int p = blockIdx.x;       // pair index 0..31
  const int h = blockIdx.y;
  const int src_chunk = (l & 7) ^ (l >> 3);
  const int rl = w * 8 + (l >> 3);

#pragma unroll 1
  for (int pass = 0; pass < 2; ++pass) {
    const int qt = pass ? (63 - p) : p;   // 64-row q-tile index
    const int qrow0 = qt * 64 + w * 16;   // this wave's first q row
    const int nkt = qt + 1;

    // Q fragments (this lane's q-row = qrow0 + lr)
    bf16x8 qf[2];
#pragma unroll
    for (int ks = 0; ks < 2; ++ks)
      qf[ks] = __builtin_bit_cast(
          bf16x8, *(const u16x8*)(QKV + (size_t)(qrow0 + lr) * 3072 +
                                  h * 64 + ks * 32 + lg * 8));

    f32x4 O[4];  // O^T: lane holds O[q=lr][d = ni*16 + lg*4 + r]
#pragma unroll
    for (int ni = 0; ni < 4; ++ni) O[ni] = (f32x4){0.f, 0.f, 0.f, 0.f};
    float m_ = -3e38f, lsum = 0.f;

    auto STAGE = [&](int buf, int kt) {
#pragma unroll
      for (int it = 0; it < 2; ++it) {
        int krow = kt * 64 + it * 32 + rl;  // token index (per-lane)
        gload16((const char*)QKV + ((size_t)krow * 3072 + 1024 + h * 64) * 2 + src_chunk * 16,
                &Ks[buf][(it * 32 + w * 8) * 64]);
        int drow = it * 32 + rl;  // head-dim index (per-lane)
        gload16((const char*)Vt + (((size_t)h * 64 + drow) * 4096 + kt * 64) * 2 + src_chunk * 16,
                &Vs[buf][(it * 32 + w * 8) * 64]);
      }
    };

    STAGE(0, 0);  // prologue
#pragma unroll 1
    for (int kt = 0; kt < nkt; ++kt) {
      const int cur = kt & 1;
      if (kt + 1 < nkt) {
        STAGE(cur ^ 1, kt + 1);  // prefetch next tile into other buffer
        asm volatile("s_waitcnt vmcnt(4)" ::: "memory");  // current tile's 4 done
      } else {
        asm volatile("s_waitcnt vmcnt(0)" ::: "memory");
      }
      __builtin_amdgcn_s_barrier();
      __builtin_amdgcn_sched_barrier(0);

      const char* kbase = (const char*)&Ks[cur][0];
      const char* vbase = (const char*)&Vs[cur][0];

      // S^T[ni] = mfma(K, Q): lane l -> S[q=lr][token = kt*64 + ni*16+lg*4+r]
      f32x4 S[4];
#pragma unroll
      for (int ni = 0; ni < 4; ++ni) {
        S[ni] = (f32x4){0.f, 0.f, 0.f, 0.f};
#pragma unroll
        for (int ks = 0; ks < 2; ++ks) {
          bf16x8 kf = *(const bf16x8*)(kbase + (ni * 16 + lr) * 128 +
                                       ((ks * 64 + lg * 16) ^ xorv));
          S[ni] = __builtin_amdgcn_mfma_f32_16x16x32_bf16(kf, qf[ks], S[ni], 0, 0, 0);
        }
      }

      // scale + causal mask (diag tile = last)
      const bool diag = (kt == qt);
#pragma unroll
      for (int ni = 0; ni < 4; ++ni)
#pragma unroll
        for (int r = 0; r < 4; ++r) {
          float s = S[ni][r] * 0.125f;
          if (diag && (ni * 16 + lg * 4 + r) > (w * 16 + lr)) s = -1e30f;
          S[ni][r] = s;
        }

      // online softmax: lane owns its q-row. in-lane reduce + xor16/xor32
      float nm = -3e38f;
#pragma unroll
      for (int ni = 0; ni < 4; ++ni)
#pragma unroll
        for (int r = 0; r < 4; ++r) nm = fmaxf(nm, S[ni][r]);
      nm = fmaxf(nm, __shfl_xor(nm, 16));
      nm = fmaxf(nm, __shfl_xor(nm, 32));
      float mn = fmaxf(m_, nm);
      float fac = __expf(m_ - mn);
      m_ = mn;
      float rs = 0.f;
#pragma unroll
      for (int ni = 0; ni < 4; ++ni)
#pragma unroll
        for (int r = 0; r < 4; ++r) {
          float pv = __expf(S[ni][r] - mn);
          S[ni][r] = pv;  // S now holds P^T
          rs += pv;
        }
      rs += __shfl_xor(rs, 16);
      rs += __shfl_xor(rs, 32);
      lsum = lsum * fac + rs;
#pragma unroll
      for (int ni = 0; ni < 4; ++ni) O[ni] *= fac;

      // P^T -> per-wave LDS [q=lr][token], packed b64 (tokens contiguous in r)
#pragma unroll
      for (int ni = 0; ni < 4; ++ni) {
        u16x4 pk;
#pragma unroll
        for (int r = 0; r < 4; ++r) pk[r] = f2bf(S[ni][r]);
        *(u16x4*)((char*)&Ps[w][0] + lr * 128 + ((ni * 32 + lg * 8) ^ xorv)) = pk;
      }
      bf16x8 pt[2];  // B-frag: P^T[token = ks*32+lg*8+j][q=lr]
#pragma unroll
      for (int ks = 0; ks < 2; ++ks)
        pt[ks] = *(const bf16x8*)((const char*)&Ps[w][0] + lr * 128 +
                                  ((ks * 64 + lg * 16) ^ xorv));

      // O^T[ni] += mfma(V^T, P^T): A = V^T[d = ni*16+lr][tokens]
#pragma unroll
      for (int ni = 0; ni < 4; ++ni) {
#pragma unroll
        for (int ks = 0; ks < 2; ++ks) {
          bf16x8 vf = *(const bf16x8*)(vbase + (ni * 16 + lr) * 128 +
                                       ((ks * 64 + lg * 16) ^ xorv));
          O[ni] = __builtin_amdgcn_mfma_f32_16x16x32_bf16(vf, pt[ks], O[ni], 0, 0, 0);
        }
      }
      asm volatile("" ::: "memory");
      __builtin_amdgcn_s_barrier();  // protect buf before next STAGE overwrites
    }

    // epilogue: normalize + act_quant (group of 64 = this head's dims).
    // lane holds O[q = qrow0+lr][d = ni*16+lg*4+r] -> whole group spans
    // this lane's 16 values + the 3 other lg-lanes with same lr.
    float rinv = 1.f / lsum;
    float o[4][4];
    float gm = 0.f;
#pragma unroll
    for (int ni = 0; ni < 4; ++ni)
#pragma unroll
      for (int r = 0; r < 4; ++r) {
        o[ni][r] = O[ni][r] * rinv;
        gm = fmaxf(gm, fabsf(o[ni][r]));
      }
    gm = fmaxf(gm, __shfl_xor(gm, 16));
    gm = fmaxf(gm, __shfl_xor(gm, 32));
    float gmc = fmaxf(gm, 1e-5f);
    float s = gmc * (1.f / 127.f);
    float inv = 127.f / gmc;
#pragma unroll
    for (int ni = 0; ni < 4; ++ni) {
      u16x4 ov;
#pragma unroll
      for (int r = 0; r < 4; ++r) {
        float q = fminf(fmaxf(rintf(o[ni][r] * inv), -127.f), 127.f) * s;
        ov[r] = f2bf(q);
      }
      *(u16x4*)(Y + (size_t)(qrow0 + lr) * 1024 + h * 64 + ni * 16 + lg * 4) = ov;
    }
  }
}

// ---------------------------------------------------------------------------
extern "C" void kernel_launch(void* const* d_in, const int* in_sizes, int n_in,
                              void* d_out, int out_size, void* d_ws, size_t ws_size,
                              hipStream_t stream) {
  const float* x  = (const float*)d_in[0];
  const float* wq = (const float*)d_in[1];
  const float* wk = (const float*)d_in[2];
  const float* wv = (const float*)d_in[3];
  const float* wo = (const float*)d_in[4];
  const float* w1 = (const float*)d_in[5];
  const float* w2 = (const float*)d_in[6];
  const float* w3 = (const float*)d_in[7];
  const float* g1 = (const float*)d_in[8];
  const float* g2 = (const float*)d_in[9];

  char* ws = (char*)d_ws;
  const size_t MB = 1024 * 1024;
  u16* sWq   = (u16*)(ws + 0 * MB);
  u16* sWk   = (u16*)(ws + 2 * MB);
  u16* sWv   = (u16*)(ws + 4 * MB);
  u16* sWo   = (u16*)(ws + 6 * MB);
  u16* sW1   = (u16*)(ws + 8 * MB);    // w1|w2 contiguous -> fused [8192,1024]
  u16* sW2   = (u16*)(ws + 16 * MB);
  u16* sW3   = (u16*)(ws + 24 * MB);
  float* partial = (float*)(ws + 32 * MB);
  float* alphas  = (float*)(ws + 32 * MB + 16384);
  u16* Vt    = (u16*)(ws + 33 * MB);   // [16][64][4096], dead before x1 written
  float* x1  = (float*)(ws + 33 * MB); // fp32 [4096,1024] (after attn)
  u16* hq    = (u16*)(ws + 49 * MB);   // bf16 [4096,1024]
  u16* zq    = (u16*)(ws + 49 * MB);   // reuses hq slot (hq dead by silu)
  u16* qkv   = (u16*)(ws + 57 * MB);   // bf16 [4096,3072]
  u16* yb    = (u16*)(ws + 81 * MB);   // bf16 [4096,1024]
  u16* y1y2  = (u16*)(ws + 57 * MB);   // bf16 [4096,8192] (qkv,yb dead)

  // weight prep
  convert_sign<<<256, 256, 0, stream>>>(wq, sWq, partial + 0 * 256, 1048576 / 4);
  convert_sign<<<256, 256, 0, stream>>>(wk, sWk, partial + 1 * 256, 1048576 / 4);
  convert_sign<<<256, 256, 0, stream>>>(wv, sWv, partial + 2 * 256, 1048576 / 4);
  convert_sign<<<256, 256, 0, stream>>>(wo, sWo, partial + 3 * 256, 1048576 / 4);
  convert_sign<<<256, 256, 0, stream>>>(w1, sW1, partial + 4 * 256, 4194304 / 4);
  convert_sign<<<256, 256, 0, stream>>>(w2, sW2, partial + 5 * 256, 4194304 / 4);
  convert_sign<<<256, 256, 0, stream>>>(w3, sW3, partial + 6 * 256, 4194304 / 4);
  finalize_alpha<<<7, 256, 0, stream>>>(partial, alphas);

  // attention branch
  rmsnorm_quant<<<4096, 256, 0, stream>>>(x, g1, hq);
  gemm_bt<false, 128><<<dim3(24, 32), 256, 0, stream>>>(hq, sWq, alphas, 10, nullptr,
                                                        qkv, 4096, 3072, 1024);
  transpose_v<<<dim3(64, 16), 256, 0, stream>>>(qkv, Vt);
  attn_kernel<<<dim3(32, 16), 256, 0, stream>>>(qkv, Vt, yb);
  gemm_bt<true, 64><<<dim3(8, 64), 256, 0, stream>>>(yb, sWo, alphas + 3, 31, x,
                                                     x1, 4096, 1024, 1024);
  // FFN branch
  rmsnorm_quant<<<4096, 256, 0, stream>>>(x1, g2, hq);
  gemm_bt<false, 128><<<dim3(64, 32), 256, 0, stream>>>(hq, sW1, alphas + 4, 12, nullptr,
                                                        y1y2, 4096, 8192, 1024);
  silu_mul_quant<<<16384, 256, 0, stream>>>(y1y2, zq);
  gemm_bt<true, 64><<<dim3(8, 64), 256, 0, stream>>>(zq, sW3, alphas + 6, 31, x1,
                                                     (float*)d_out, 4096, 1024, 4096);
}

// Round 6
// 332.074 us; speedup vs baseline: 1.8503x; 1.0976x over previous
//
#include <hip/hip_runtime.h>
#include <math.h>

// ============================================================================
// BitNet transformer block, MI355X (gfx950).  Round 6.
// R5 -> R6:
//  (a) attn: 4 blocks/CU (grid (16,64), qt = y<32?y:95-y -> any stride-256
//      round-robin gives every CU exactly 130 k-iters). Was 2 blocks/CU.
//  (b) attn: exp2-domain softmax (fold 0.125*log2e), T13 defer-rescale via
//      __ballot (skip O-rescale when tile max within +8 of running max).
//  (c) convert_sign: 7 launches fused into one (grid y = weight index).
// ws layout (MB = 2^20), peak 121 MB:
//   0..32    sign weights (wq@0,wk@2,wv@4,wo@6, w1@8,w2@16 (contig), w3@24)
//   32..33   alpha partials (7*256 f32); alphas (7 f32) at +16KB
//   33..49   Vt bf16 [16][64][4096] (live transpose->attn), then x1 fp32
//   49..57   hq bf16 (live rmsnorm->gemm), then zq bf16 (silu->w3 gemm)
//   57..81   qkv bf16 [4096,3072] (live ->attn); then y1y2 [4096,8192] 57..121
//   81..89   yb bf16 (attn->wo gemm), then overlaid by y1y2
// ============================================================================

typedef unsigned short u16;
typedef __attribute__((ext_vector_type(4))) float f32x4;
typedef __attribute__((ext_vector_type(4))) unsigned short u16x4;
typedef __attribute__((ext_vector_type(8))) unsigned short u16x8;
typedef __attribute__((ext_vector_type(8))) __bf16 bf16x8;

#define DEV static __device__ __forceinline__

DEV float bf2f(u16 u) { union { unsigned i; float f; } c; c.i = ((unsigned)u) << 16; return c.f; }
DEV u16 f2bf(float f) { __bf16 b = (__bf16)f; return __builtin_bit_cast(u16, b); }

DEV void gload16(const void* g, void* l) {
  __builtin_amdgcn_global_load_lds((__attribute__((address_space(1))) void*)g,
                                   (__attribute__((address_space(3))) void*)l,
                                   16, 0, 0);
}

// ---------------------------------------------------------------------------
// Weight prep: sign(w) -> bf16 {+1,-1,0}, block-partial sums of |w|.
// One fused kernel: blockIdx.y = weight index 0..6.
// ---------------------------------------------------------------------------
__global__ __launch_bounds__(256) void convert_sign_all(
    const float* __restrict__ w0, const float* __restrict__ w1,
    const float* __restrict__ w2, const float* __restrict__ w3,
    const float* __restrict__ w4, const float* __restrict__ w5,
    const float* __restrict__ w6, u16* __restrict__ sgn_base,
    float* __restrict__ partial) {
  __shared__ float red[4];
  const int wi = blockIdx.y;
  const float* srcs[7] = {w0, w1, w2, w3, w4, w5, w6};
  const size_t offs[7] = {0, 1048576, 2097152, 3145728, 4194304, 8388608, 12582912};
  const float* w = srcs[wi];
  u16* sgn = sgn_base + offs[wi];
  const int n4 = (wi < 4) ? 262144 : 1048576;

  float s = 0.f;
  for (int i = blockIdx.x * 256 + threadIdx.x; i < n4; i += 256 * 256) {
    f32x4 v = ((const f32x4*)w)[i];
    u16x4 o;
#pragma unroll
    for (int j = 0; j < 4; ++j) {
      float f = v[j];
      o[j] = f > 0.f ? (u16)0x3F80 : (f < 0.f ? (u16)0xBF80 : (u16)0);
      s += fabsf(f);
    }
    ((u16x4*)sgn)[i] = o;
  }
#pragma unroll
  for (int off = 32; off >= 1; off >>= 1) s += __shfl_xor(s, off);
  if ((threadIdx.x & 63) == 0) red[threadIdx.x >> 6] = s;
  __syncthreads();
  if (threadIdx.x == 0)
    partial[wi * 256 + blockIdx.x] = red[0] + red[1] + red[2] + red[3];
}

__global__ __launch_bounds__(256) void finalize_alpha(
    const float* __restrict__ partial, float* __restrict__ alphas) {
  __shared__ float red[4];
  int wi = blockIdx.x;  // 0..6
  float v = partial[wi * 256 + threadIdx.x];
#pragma unroll
  for (int off = 32; off >= 1; off >>= 1) v += __shfl_xor(v, off);
  if ((threadIdx.x & 63) == 0) red[threadIdx.x >> 6] = v;
  __syncthreads();
  if (threadIdx.x == 0)
    alphas[wi] = (red[0] + red[1] + red[2] + red[3]) *
                 (wi < 4 ? (1.f / 1048576.f) : (1.f / 4194304.f));
}

// ---------------------------------------------------------------------------
// RMSNorm + act_quant (group 64). One block per row of 1024.
// ---------------------------------------------------------------------------
__global__ __launch_bounds__(256) void rmsnorm_quant(
    const float* __restrict__ x, const float* __restrict__ g, u16* __restrict__ out) {
  __shared__ float red[4];
  const int row = blockIdx.x, t = threadIdx.x;
  f32x4 v = ((const f32x4*)(x + (size_t)row * 1024))[t];
  float ss = v[0] * v[0] + v[1] * v[1] + v[2] * v[2] + v[3] * v[3];
#pragma unroll
  for (int off = 32; off >= 1; off >>= 1) ss += __shfl_xor(ss, off);
  if ((t & 63) == 0) red[t >> 6] = ss;
  __syncthreads();
  float tot = red[0] + red[1] + red[2] + red[3];
  float rinv = rsqrtf(tot * (1.f / 1024.f) + 1e-6f);
  f32x4 gg = ((const f32x4*)g)[t];
  float n[4];
#pragma unroll
  for (int j = 0; j < 4; ++j) n[j] = v[j] * rinv * gg[j];
  float gm = fmaxf(fmaxf(fabsf(n[0]), fabsf(n[1])), fmaxf(fabsf(n[2]), fabsf(n[3])));
#pragma unroll
  for (int off = 1; off <= 8; off <<= 1) gm = fmaxf(gm, __shfl_xor(gm, off));
  float s = fmaxf(gm, 1e-5f) / 127.0f;
  u16x4 o;
#pragma unroll
  for (int j = 0; j < 4; ++j) {
    float q = fminf(fmaxf(rintf(n[j] / s), -127.f), 127.f) * s;
    o[j] = f2bf(q);
  }
  ((u16x4*)out)[(size_t)row * 256 + t] = o;
}

// ---------------------------------------------------------------------------
// silu(y1)*y2 + act_quant. y1y2 fused [4096, 8192].
// ---------------------------------------------------------------------------
__global__ __launch_bounds__(256) void silu_mul_quant(
    const u16* __restrict__ y1y2, u16* __restrict__ zq) {
  size_t idx = (size_t)blockIdx.x * 1024 + threadIdx.x * 4;  // 0..16M
  size_t row = idx >> 12, c = idx & 4095;
  u16x4 a4 = *(const u16x4*)(y1y2 + row * 8192 + c);
  u16x4 b4 = *(const u16x4*)(y1y2 + row * 8192 + 4096 + c);
  float z[4];
#pragma unroll
  for (int j = 0; j < 4; ++j) {
    float a = bf2f(a4[j]);
    z[j] = a / (1.f + __expf(-a)) * bf2f(b4[j]);
  }
  float gm = fmaxf(fmaxf(fabsf(z[0]), fabsf(z[1])), fmaxf(fabsf(z[2]), fabsf(z[3])));
#pragma unroll
  for (int off = 1; off <= 8; off <<= 1) gm = fmaxf(gm, __shfl_xor(gm, off));
  float s = fmaxf(gm, 1e-5f) / 127.0f;
  u16x4 o;
#pragma unroll
  for (int j = 0; j < 4; ++j) {
    float q = fminf(fmaxf(rintf(z[j] / s), -127.f), 127.f) * s;
    o[j] = f2bf(q);
  }
  *(u16x4*)(zq + idx) = o;
}

// ---------------------------------------------------------------------------
// V transpose: qkv[:,2048+h*64 .. +63] -> Vt[h][d][t]  ([16][64][4096] bf16).
// ---------------------------------------------------------------------------
__global__ __launch_bounds__(256) void transpose_v(
    const u16* __restrict__ qkv, u16* __restrict__ Vt) {
  __shared__ u16 T[64][65];
  const int tt = blockIdx.x, h = blockIdx.y, tid = threadIdx.x;
#pragma unroll
  for (int i = 0; i < 2; ++i) {
    int idx = i * 2048 + tid * 8;
    int trow = idx >> 6, dcol = idx & 63;
    u16x8 v = *(const u16x8*)(qkv + (size_t)(tt * 64 + trow) * 3072 + 2048 + h * 64 + dcol);
#pragma unroll
    for (int j = 0; j < 8; ++j) T[dcol + j][trow] = v[j];
  }
  __syncthreads();
#pragma unroll
  for (int i = 0; i < 2; ++i) {
    int idx = i * 2048 + tid * 8;
    int drow = idx >> 6, tcol = idx & 63;
    u16x8 v;
#pragma unroll
    for (int j = 0; j < 8; ++j) v[j] = T[drow][tcol + j];
    *(u16x8*)(Vt + ((size_t)h * 64 + drow) * 4096 + tt * 64 + tcol) = v;
  }
}

// ---------------------------------------------------------------------------
// GEMM: C[M,N] = alpha[bcol>>ashift] * (A[M,K] @ B[N,K]^T) (+res).
// BMxN=128 tile (BM = 128 or 64), BK=64, 4 waves, global_load_lds w=16,
// XOR swizzle. BM=64 -> 2x the blocks for small-grid shapes (occupancy).
// ---------------------------------------------------------------------------
template <bool RES, int BM>
__global__ __launch_bounds__(256) void gemm_bt(
    const u16* __restrict__ A, const u16* __restrict__ B,
    const float* __restrict__ alpha, int ashift, const float* __restrict__ res,
    void* __restrict__ Cout, int M, int N, int K) {
  constexpr int NI = (BM == 128) ? 4 : 2;    // per-wave N fragments
  constexpr int WNE = (BM == 128) ? 64 : 32; // per-wave N extent
  __shared__ u16 As[BM * 64];
  __shared__ u16 Bs[128 * 64];
  const int tid = threadIdx.x;
  const int l = tid & 63, w = tid >> 6;
  const int wm = (BM == 128) ? (w >> 1) : 0;
  const int wn = (BM == 128) ? (w & 1) : w;
  const int lr = l & 15, lg = l >> 4;
  const int xorv = (l & 7) << 4;
  const int brow = blockIdx.y * BM;
  const int bcol = blockIdx.x * 128;
  const int src_chunk = (l & 7) ^ (l >> 3);
  const int rl = w * 8 + (l >> 3);

  f32x4 acc[4][NI];
#pragma unroll
  for (int i = 0; i < 4; ++i)
#pragma unroll
    for (int j = 0; j < NI; ++j) acc[i][j] = (f32x4){0.f, 0.f, 0.f, 0.f};

  const char* Ag = (const char*)A;
  const char* Bg = (const char*)B;
  const int nkt = K >> 6;
  for (int kt = 0; kt < nkt; ++kt) {
    __syncthreads();
    const size_t kb = (size_t)kt * 128 + src_chunk * 16;
#pragma unroll
    for (int it = 0; it < BM / 32; ++it)
      gload16(Ag + (size_t)(brow + it * 32 + rl) * (size_t)(K * 2) + kb,
              &As[(it * 32 + w * 8) * 64]);
#pragma unroll
    for (int it = 0; it < 4; ++it)
      gload16(Bg + (size_t)(bcol + it * 32 + rl) * (size_t)(K * 2) + kb,
              &Bs[(it * 32 + w * 8) * 64]);
    __syncthreads();

    bf16x8 af[4][2], bfr[NI][2];
#pragma unroll
    for (int mi = 0; mi < 4; ++mi)
#pragma unroll
      for (int ks = 0; ks < 2; ++ks) {
        int row = wm * 64 + mi * 16 + lr;
        af[mi][ks] = *(const bf16x8*)((const char*)As + row * 128 + ((ks * 64 + lg * 16) ^ xorv));
      }
#pragma unroll
    for (int ni = 0; ni < NI; ++ni)
#pragma unroll
      for (int ks = 0; ks < 2; ++ks) {
        int row = wn * WNE + ni * 16 + lr;
        bfr[ni][ks] = *(const bf16x8*)((const char*)Bs + row * 128 + ((ks * 64 + lg * 16) ^ xorv));
      }
#pragma unroll
    for (int ks = 0; ks < 2; ++ks)
#pragma unroll
      for (int mi = 0; mi < 4; ++mi)
#pragma unroll
        for (int ni = 0; ni < NI; ++ni)
          acc[mi][ni] = __builtin_amdgcn_mfma_f32_16x16x32_bf16(
              af[mi][ks], bfr[ni][ks], acc[mi][ni], 0, 0, 0);
  }

  const float scale = alpha[bcol >> ashift];
#pragma unroll
  for (int mi = 0; mi < 4; ++mi)
#pragma unroll
    for (int ni = 0; ni < NI; ++ni)
#pragma unroll
      for (int r = 0; r < 4; ++r) {
        int row = brow + wm * 64 + mi * 16 + lg * 4 + r;
        int col = bcol + wn * WNE + ni * 16 + lr;
        float vv = acc[mi][ni][r] * scale;
        if (RES)
          ((float*)Cout)[(size_t)row * N + col] = res[(size_t)row * N + col] + vv;
        else
          ((u16*)Cout)[(size_t)row * N + col] = f2bf(vv);
      }
}

// ---------------------------------------------------------------------------
// Causal flash attention + act_quant epilogue.  SWAPPED-OPERAND form.
// Grid (16 heads, 64 q-tiles): qt = y<32 ? y : 95-y, so any stride-256
// round-robin dispatch gives every CU 4 blocks totalling 130 k-iters.
// 4 blocks/CU (LDS 40KB). exp2-domain softmax + defer-rescale (T13).
// ---------------------------------------------------------------------------
__global__ __launch_bounds__(256) void attn_kernel(
    const u16* __restrict__ QKV, const u16* __restrict__ Vt, u16* __restrict__ Y) {
  __shared__ u16 Ks[2][64 * 64];  // [k-token 64][d 64] swizzled
  __shared__ u16 Vs[2][64 * 64];  // [d 64][k-token 64] swizzled
  __shared__ u16 Ps[4][16 * 64];  // per-wave P^T as [q 16][token 64] swizzled

  const int tid = threadIdx.x;
  const int l = tid & 63, w = tid >> 6;
  const int lr = l & 15, lg = l >> 4;
  const int xorv = (l & 7) << 4;  // == (lr&7)<<4
  const int h = blockIdx.x;
  const int y = blockIdx.y;
  const int qt = (y < 32) ? y : (95 - y);  // 64-row q-tile index
  const int src_chunk = (l & 7) ^ (l >> 3);
  const int rl = w * 8 + (l >> 3);
  const float SC = 0.18033688f;  // 0.125 * log2(e): softmax in exp2 domain

  const int qrow0 = qt * 64 + w * 16;  // this wave's first q row
  const int nkt = qt + 1;

  // Q fragments (this lane's q-row = qrow0 + lr)
  bf16x8 qf[2];
#pragma unroll
  for (int ks = 0; ks < 2; ++ks)
    qf[ks] = __builtin_bit_cast(
        bf16x8, *(const u16x8*)(QKV + (size_t)(qrow0 + lr) * 3072 +
                                h * 64 + ks * 32 + lg * 8));

  f32x4 O[4];  // O^T: lane holds O[q=lr][d = ni*16 + lg*4 + r]
#pragma unroll
  for (int ni = 0; ni < 4; ++ni) O[ni] = (f32x4){0.f, 0.f, 0.f, 0.f};
  float m_ = -3e38f, lsum = 0.f;

  auto STAGE = [&](int buf, int kt) {
#pragma unroll
    for (int it = 0; it < 2; ++it) {
      int krow = kt * 64 + it * 32 + rl;  // token index (per-lane)
      gload16((const char*)QKV + ((size_t)krow * 3072 + 1024 + h * 64) * 2 + src_chunk * 16,
              &Ks[buf][(it * 32 + w * 8) * 64]);
      int drow = it * 32 + rl;  // head-dim index (per-lane)
      gload16((const char*)Vt + (((size_t)h * 64 + drow) * 4096 + kt * 64) * 2 + src_chunk * 16,
              &Vs[buf][(it * 32 + w * 8) * 64]);
    }
  };

  STAGE(0, 0);  // prologue
#pragma unroll 1
  for (int kt = 0; kt < nkt; ++kt) {
    const int cur = kt & 1;
    if (kt + 1 < nkt) {
      STAGE(cur ^ 1, kt + 1);  // prefetch next tile into other buffer
      asm volatile("s_waitcnt vmcnt(4)" ::: "memory");  // current tile's 4 done
    } else {
      asm volatile("s_waitcnt vmcnt(0)" ::: "memory");
    }
    __builtin_amdgcn_s_barrier();
    __builtin_amdgcn_sched_barrier(0);

    const char* kbase = (const char*)&Ks[cur][0];
    const char* vbase = (const char*)&Vs[cur][0];

    // S^T[ni] = mfma(K, Q): lane l -> S[q=lr][token = kt*64 + ni*16+lg*4+r]
    f32x4 S[4];
#pragma unroll
    for (int ni = 0; ni < 4; ++ni) {
      S[ni] = (f32x4){0.f, 0.f, 0.f, 0.f};
#pragma unroll
      for (int ks = 0; ks < 2; ++ks) {
        bf16x8 kf = *(const bf16x8*)(kbase + (ni * 16 + lr) * 128 +
                                     ((ks * 64 + lg * 16) ^ xorv));
        S[ni] = __builtin_amdgcn_mfma_f32_16x16x32_bf16(kf, qf[ks], S[ni], 0, 0, 0);
      }
    }

    // scale to exp2 domain + causal mask (diag tile = last)
    const bool diag = (kt == qt);
#pragma unroll
    for (int ni = 0; ni < 4; ++ni)
#pragma unroll
      for (int r = 0; r < 4; ++r) {
        float s = S[ni][r] * SC;
        if (diag && (ni * 16 + lg * 4 + r) > (w * 16 + lr)) s = -1e30f;
        S[ni][r] = s;
      }

    // online softmax (lane owns its q-row; row spans lanes lr, lr+16,+32,+48)
    float nm = -3e38f;
#pragma unroll
    for (int ni = 0; ni < 4; ++ni)
#pragma unroll
      for (int r = 0; r < 4; ++r) nm = fmaxf(nm, S[ni][r]);
    nm = fmaxf(nm, __shfl_xor(nm, 16));
    nm = fmaxf(nm, __shfl_xor(nm, 32));
    // T13 defer-rescale: only rescale when some row's max grew past m_+8
    if (__ballot(nm > m_ + 8.f)) {
      float mn = fmaxf(m_, nm);
      float fac = exp2f(m_ - mn);
      m_ = mn;
      lsum *= fac;
#pragma unroll
      for (int ni = 0; ni < 4; ++ni) O[ni] *= fac;
    }
    float rs = 0.f;
#pragma unroll
    for (int ni = 0; ni < 4; ++ni)
#pragma unroll
      for (int r = 0; r < 4; ++r) {
        float pv = exp2f(S[ni][r] - m_);  // bounded by 2^8 under defer
        S[ni][r] = pv;                    // S now holds P^T
        rs += pv;
      }
    rs += __shfl_xor(rs, 16);
    rs += __shfl_xor(rs, 32);
    lsum += rs;

    // P^T -> per-wave LDS [q=lr][token], packed b64 (tokens contiguous in r)
#pragma unroll
    for (int ni = 0; ni < 4; ++ni) {
      u16x4 pk;
#pragma unroll
      for (int r = 0; r < 4; ++r) pk[r] = f2bf(S[ni][r]);
      *(u16x4*)((char*)&Ps[w][0] + lr * 128 + ((ni * 32 + lg * 8) ^ xorv)) = pk;
    }
    bf16x8 pt[2];  // B-frag: P^T[token = ks*32+lg*8+j][q=lr]
#pragma unroll
    for (int ks = 0; ks < 2; ++ks)
      pt[ks] = *(const bf16x8*)((const char*)&Ps[w][0] + lr * 128 +
                                ((ks * 64 + lg * 16) ^ xorv));

    // O^T[ni] += mfma(V^T, P^T): A = V^T[d = ni*16+lr][tokens]
#pragma unroll
    for (int ni = 0; ni < 4; ++ni) {
#pragma unroll
      for (int ks = 0; ks < 2; ++ks) {
        bf16x8 vf = *(const bf16x8*)(vbase + (ni * 16 + lr) * 128 +
                                     ((ks * 64 + lg * 16) ^ xorv));
        O[ni] = __builtin_amdgcn_mfma_f32_16x16x32_bf16(vf, pt[ks], O[ni], 0, 0, 0);
      }
    }
    asm volatile("" ::: "memory");
    __builtin_amdgcn_s_barrier();  // protect buf before next STAGE overwrites
  }

  // epilogue: normalize + act_quant (group of 64 = this head's dims).
  float rinv = 1.f / lsum;
  float o[4][4];
  float gm = 0.f;
#pragma unroll
  for (int ni = 0; ni < 4; ++ni)
#pragma unroll
    for (int r = 0; r < 4; ++r) {
      o[ni][r] = O[ni][r] * rinv;
      gm = fmaxf(gm, fabsf(o[ni][r]));
    }
  gm = fmaxf(gm, __shfl_xor(gm, 16));
  gm = fmaxf(gm, __shfl_xor(gm, 32));
  float gmc = fmaxf(gm, 1e-5f);
  float s = gmc * (1.f / 127.f);
  float inv = 127.f / gmc;
#pragma unroll
  for (int ni = 0; ni < 4; ++ni) {
    u16x4 ov;
#pragma unroll
    for (int r = 0; r < 4; ++r) {
      float q = fminf(fmaxf(rintf(o[ni][r] * inv), -127.f), 127.f) * s;
      ov[r] = f2bf(q);
    }
    *(u16x4*)(Y + (size_t)(qrow0 + lr) * 1024 + h * 64 + ni * 16 + lg * 4) = ov;
  }
}

// ---------------------------------------------------------------------------
extern "C" void kernel_launch(void* const* d_in, const int* in_sizes, int n_in,
                              void* d_out, int out_size, void* d_ws, size_t ws_size,
                              hipStream_t stream) {
  const float* x  = (const float*)d_in[0];
  const float* wq = (const float*)d_in[1];
  const float* wk = (const float*)d_in[2];
  const float* wv = (const float*)d_in[3];
  const float* wo = (const float*)d_in[4];
  const float* w1 = (const float*)d_in[5];
  const float* w2 = (const float*)d_in[6];
  const float* w3 = (const float*)d_in[7];
  const float* g1 = (const float*)d_in[8];
  const float* g2 = (const float*)d_in[9];

  char* ws = (char*)d_ws;
  const size_t MB = 1024 * 1024;
  u16* sgn   = (u16*)ws;               // all sign weights (offsets in kernel)
  u16* sWq   = (u16*)(ws + 0 * MB);
  u16* sWo   = (u16*)(ws + 6 * MB);
  u16* sW1   = (u16*)(ws + 8 * MB);    // w1|w2 contiguous -> fused [8192,1024]
  u16* sW3   = (u16*)(ws + 24 * MB);
  float* partial = (float*)(ws + 32 * MB);
  float* alphas  = (float*)(ws + 32 * MB + 16384);
  u16* Vt    = (u16*)(ws + 33 * MB);   // [16][64][4096], dead before x1 written
  float* x1  = (float*)(ws + 33 * MB); // fp32 [4096,1024] (after attn)
  u16* hq    = (u16*)(ws + 49 * MB);   // bf16 [4096,1024]
  u16* zq    = (u16*)(ws + 49 * MB);   // reuses hq slot (hq dead by silu)
  u16* qkv   = (u16*)(ws + 57 * MB);   // bf16 [4096,3072]
  u16* yb    = (u16*)(ws + 81 * MB);   // bf16 [4096,1024]
  u16* y1y2  = (u16*)(ws + 57 * MB);   // bf16 [4096,8192] (qkv,yb dead)

  // weight prep (fused; grid y = weight index)
  convert_sign_all<<<dim3(256, 7), 256, 0, stream>>>(wq, wk, wv, wo, w1, w2, w3,
                                                     sgn, partial);
  finalize_alpha<<<7, 256, 0, stream>>>(partial, alphas);

  // attention branch
  rmsnorm_quant<<<4096, 256, 0, stream>>>(x, g1, hq);
  gemm_bt<false, 128><<<dim3(24, 32), 256, 0, stream>>>(hq, sWq, alphas, 10, nullptr,
                                                        qkv, 4096, 3072, 1024);
  transpose_v<<<dim3(64, 16), 256, 0, stream>>>(qkv, Vt);
  attn_kernel<<<dim3(16, 64), 256, 0, stream>>>(qkv, Vt, yb);
  gemm_bt<true, 64><<<dim3(8, 64), 256, 0, stream>>>(yb, sWo, alphas + 3, 31, x,
                                                     x1, 4096, 1024, 1024);
  // FFN branch
  rmsnorm_quant<<<4096, 256, 0, stream>>>(x1, g2, hq);
  gemm_bt<false, 128><<<dim3(64, 32), 256, 0, stream>>>(hq, sW1, alphas + 4, 12, nullptr,
                                                        y1y2, 4096, 8192, 1024);
  silu_mul_quant<<<16384, 256, 0, stream>>>(y1y2, zq);
  gemm_bt<true, 64><<<dim3(8, 64), 256, 0, stream>>>(zq, sW3, alphas + 6, 31, x1,
                                                     (float*)d_out, 4096, 1024, 4096);
}